// Round 3
// baseline (473.752 us; speedup 1.0000x reference)
//
#include <hip/hip_runtime.h>
#include <hip/hip_bf16.h>
#include <stdint.h>

#define B_   2
#define S_   4096
#define H_   2048
#define NH_  8
#define D_   128
#define KD_  1024
#define MR   (B_ * S_)          // 8192 rows
#define NQKVZ 4096              // q|k|v|z concatenated width

typedef __attribute__((ext_vector_type(8))) short bf16x8;
typedef __attribute__((ext_vector_type(4))) float f32x4;

__device__ __forceinline__ short f2bf(float f) {
    union { float f; uint32_t u; } v; v.f = f;
    uint32_t r = v.u + 0x7FFF + ((v.u >> 16) & 1);   // RNE
    return (short)(r >> 16);
}
__device__ __forceinline__ float bf2f(unsigned short u) {
    union { uint32_t u; float f; } v; v.u = (uint32_t)u << 16; return v.f;
}

__device__ __forceinline__ void async_ld16(const void* g, void* l) {
    __builtin_amdgcn_global_load_lds(
        (const __attribute__((address_space(1))) uint32_t*)g,
        (__attribute__((address_space(3))) uint32_t*)l, 16, 0, 0);
}

// ---------------- fused: x row -> bf16 + bgag skinny GEMM ----------------
__global__ __launch_bounds__(256) void k_cvt_bgag(const float* __restrict__ x,
                                                  short* __restrict__ xb,
                                                  const float* __restrict__ Wb,
                                                  const float* __restrict__ Wa,
                                                  float* __restrict__ bgag) {
    const int m = blockIdx.x, t = threadIdx.x;
    __shared__ float xs[2048];
    __shared__ float part[256];
    const float4* xr = (const float4*)(x + (size_t)m * H_);
    float4 a = xr[t], b = xr[t + 256];
    ((float4*)xs)[t] = a;
    ((float4*)xs)[t + 256] = b;
    short4 oa, ob;
    oa.x = f2bf(a.x); oa.y = f2bf(a.y); oa.z = f2bf(a.z); oa.w = f2bf(a.w);
    ob.x = f2bf(b.x); ob.y = f2bf(b.y); ob.z = f2bf(b.z); ob.w = f2bf(b.w);
    short4* xo = (short4*)(xb + (size_t)m * H_);
    xo[t] = oa;
    xo[t + 256] = ob;
    __syncthreads();
    int col = t & 15, seg = t >> 4;
    const float* W = (col < 8) ? Wb : Wa;
    int c = col & 7;
    float acc = 0.f;
    int kb = seg * 128;
    for (int k = 0; k < 128; k++) acc += xs[kb + k] * W[(size_t)(kb + k) * 8 + c];
    part[t] = acc;
    __syncthreads();
    if (t < 16) {
        float s = 0.f;
        for (int j = 0; j < 16; j++) s += part[j * 16 + t];
        bgag[(size_t)m * 16 + t] = s;   // [0..8)=bg, [8..16)=ag
    }
}

// ---------------- transpose + convert: W (KxN f32) -> Wt (NxK bf16) ----------------
__global__ __launch_bounds__(256) void k_transpose_cvt(const float* __restrict__ W,
                                                       short* __restrict__ Wt,
                                                       int K, int N) {
    __shared__ float tile[32][33];
    int n0 = blockIdx.x * 32, k0 = blockIdx.y * 32;
    int tx = threadIdx.x, ty = threadIdx.y;   // 32 x 8
#pragma unroll
    for (int i = 0; i < 32; i += 8)
        tile[ty + i][tx] = W[(size_t)(k0 + ty + i) * N + n0 + tx];
    __syncthreads();
#pragma unroll
    for (int i = 0; i < 32; i += 8)
        Wt[(size_t)(n0 + ty + i) * K + k0 + tx] = f2bf(tile[tx][ty + i]);
}

// ---------------- RoPE table: ctab[s][i] = {cos(s*inv_i), sin(s*inv_i)} ----------------
__global__ __launch_bounds__(256) void k_ropetab(float2* __restrict__ ctab) {
    int idx = blockIdx.x * 256 + threadIdx.x;   // S_*64
    int i = idx & 63, s = idx >> 6;
    float inv = exp2f(-(float)i * (2.0f / 128.0f) * 19.931568569324174f);
    float f = (float)s * inv;
    float sn, cs;
    sincosf(f, &sn, &cs);
    ctab[idx] = make_float2(cs, sn);
}

// ============ 256x256 MFMA GEMM — 2 phases per K-tile (R3 merge) ============
// C = A(MxK bf16) * Bt(NxK bf16)^T.  BM=256, BK=64, 8 waves (2M x 4N),
// double-buffered LDS, counted vmcnt (never 0 in main loop), XOR-swizzled
// chunks (swizzle on global src for global_load_lds + on ds_read addr).
// R3: merged mh0/mh1 sub-phases -> 2 phases/K-tile, 32 MFMA per barrier pair
// (halves the per-phase barrier+lgkm fixed cost that R2 showed dominates).
// Phase = {12 ds_read + stage one (A+B) half-pair -> barrier -> lgkmcnt(0)
//          -> 32 MFMA -> vmcnt(8) drain -> barrier}.
// EPI=0: f32 C stores. EPI=1: fused RoPE on cols<2048, packed bf16 stores.
#define PHASE_SYNC_BEGIN() \
    asm volatile("s_barrier" ::: "memory"); \
    asm volatile("s_waitcnt lgkmcnt(0)" ::: "memory"); \
    __builtin_amdgcn_sched_barrier(0); \
    __builtin_amdgcn_s_setprio(1)
#define PHASE_SYNC_END_DRAIN() \
    __builtin_amdgcn_s_setprio(0); \
    asm volatile("s_waitcnt vmcnt(%0)" :: "n"(2 * (2 + LB)) : "memory"); \
    asm volatile("s_barrier" ::: "memory")
#define LDA_ALL(KH) \
    _Pragma("unroll") for (int i = 0; i < 8; i++) \
        afr[i] = *(const bf16x8*)(base + (KH) * AHB + (wm + i * 16 + mrow) * 64 + kcA)
#define LDB_F(KH) \
    _Pragma("unroll") for (int j = 0; j < NF; j++) \
        bfr[j] = *(const bf16x8*)(base + 2 * AHB + (KH) * BHB + (wn + j * 16 + mrow) * 64 + kcA)
#define MFMA_ALL() \
    _Pragma("unroll") for (int i = 0; i < 8; i++) \
    _Pragma("unroll") for (int j = 0; j < NF; j++) \
        acc[i][j] = __builtin_amdgcn_mfma_f32_16x16x32_bf16(afr[i], bfr[j], acc[i][j], 0, 0, 0)

template <int BN, int EPI>
__global__ __launch_bounds__(512, 2) void k_gemm256(const short* __restrict__ A,
                                                    const short* __restrict__ Bt,
                                                    float* __restrict__ Cf,
                                                    unsigned short* __restrict__ Cb,
                                                    const float2* __restrict__ ctab,
                                                    int M, int N, int K) {
    constexpr int BM = 256;
    constexpr int NF = BN / 64;       // n-frags per wave
    constexpr int LB = BN / 128;      // B global_load_lds per half-tile per thread
    constexpr int AHB = BM * 64;      // bytes per A kh-half (256 rows x 32 bf16)
    constexpr int BHB = BN * 64;
    constexpr int BUFB = 2 * AHB + 2 * BHB;
    __shared__ __align__(16) char lds[2 * BUFB];

    const int t = threadIdx.x;
    const int lane = t & 63, wave = t >> 6;
    const int mrow = lane & 15;
    // read-side swizzle: chunk kc_lds = kc_global ^ ((row>>1)&3); row base is
    // a multiple of 16 so f(row) reduces to (mrow>>1)&3 (lane-constant).
    const int kcA = (((lane >> 4) ^ ((mrow >> 1) & 3)) * 16);

    // XCD-aware bijective swizzle (grid % 8 == 0 for both call sites).
    // bn varies FASTEST within an XCD chunk (B-panels co-resident in L2).
    const int nwg = gridDim.x;
    const int w0 = blockIdx.x;
    const int wg = (w0 & 7) * (nwg >> 3) + (w0 >> 3);
    const int NB = N / BN;
    const int bn = (wg % NB) * BN;
    const int bm = (wg / NB) * BM;

    const int wm = (wave >> 2) * 128;
    const int wn = (wave & 3) * (BN / 4);

    const short* __restrict__ Ab = A + (size_t)bm * K;
    const short* __restrict__ Bb = Bt + (size_t)bn * K;

    // per-thread stage offsets: chunk c -> (row=c>>2, kc=c&3); global source
    // uses kc ^ ((row>>1)&3) so that linear LDS + swizzled read = identity.
    int aoff[2], adst[2];
#pragma unroll
    for (int l = 0; l < 2; l++) {
        int c = t + l * 512;
        int row = c >> 2;
        int kcg = (c & 3) ^ ((row >> 1) & 3);
        aoff[l] = row * K + kcg * 8;
        adst[l] = c * 16;
    }
    int boff[LB], bdst[LB];
#pragma unroll
    for (int l = 0; l < LB; l++) {
        int c = t + l * 512;
        int row = c >> 2;
        int kcg = (c & 3) ^ ((row >> 1) & 3);
        boff[l] = row * K + kcg * 8;
        bdst[l] = c * 16;
    }

    const int NT = K >> 6;

    auto stageA = [&](int kt, int kh, int p) {
        const short* g = Ab + kt * 64 + kh * 32;
        char* d = lds + p * BUFB + kh * AHB;
#pragma unroll
        for (int l = 0; l < 2; l++) async_ld16(g + aoff[l], d + adst[l]);
    };
    auto stageB = [&](int kt, int kh, int p) {
        const short* g = Bb + kt * 64 + kh * 32;
        char* d = lds + p * BUFB + 2 * AHB + kh * BHB;
#pragma unroll
        for (int l = 0; l < LB; l++) async_ld16(g + boff[l], d + bdst[l]);
    };

    f32x4 acc[8][NF] = {};

    // ---- prologue: 3 half-pair groups in flight (12 instrs) ----
    stageA(0, 0, 0); stageB(0, 0, 0);      // group 1: (0,kh0)
    stageA(0, 1, 0); stageB(0, 1, 0);      // group 2: (0,kh1)
    {
        int k1 = (NT > 1) ? 1 : 0;
        stageA(k1, 0, 1); stageB(k1, 0, 1); // group 3: (1,kh0)
    }
    // drain group 1 only; leave 2 groups (8 instrs) in flight
    asm volatile("s_waitcnt vmcnt(%0)" :: "n"(2 * (2 + LB)) : "memory");
    asm volatile("s_barrier" ::: "memory");

    // ---- main loop: 2 phases per K-tile ----
    // stage ledger (groups of 2+LB instrs, uniform):
    //   phase A (kh0): stage S_A(kt) = (kt+1,kh1)->buf[p^1]; drain vmcnt(8)
    //       waits S_A(kt-1) = (kt,kh1)  [needed by phase B reads]   ✓
    //   phase B (kh1): stage S_B(kt) = (kt+2,kh0)->buf[p];   drain vmcnt(8)
    //       waits S_B(kt-1) = (kt+1,kh0) [needed by next phase A]   ✓
    // WAR: S_A(kt) overwrites buf[p^1].kh1, last read in phase B of kt-1
    //   (barrier-ordered); S_B(kt) overwrites buf[p].kh0, last read in
    //   phase A of kt (barrier-ordered). Race-free.
    // late stages clamp kt (rewrites last tile into dead region; counts uniform)
    for (int kt = 0; kt < NT; kt++) {
        const int p = kt & 1;
        const char* base = lds + p * BUFB;
        const int k1 = (kt + 1 < NT) ? (kt + 1) : (NT - 1);
        const int k2 = (kt + 2 < NT) ? (kt + 2) : (NT - 1);
        bf16x8 afr[8], bfr[NF];

        // phase A: kh0, full 128-row A + B, 32 MFMA
        LDB_F(0);
        LDA_ALL(0);
        stageA(k1, 1, p ^ 1); stageB(k1, 1, p ^ 1);
        PHASE_SYNC_BEGIN();
        MFMA_ALL();
        PHASE_SYNC_END_DRAIN();

        // phase B: kh1
        LDB_F(1);
        LDA_ALL(1);
        stageA(k2, 0, p); stageB(k2, 0, p);
        PHASE_SYNC_BEGIN();
        MFMA_ALL();
        PHASE_SYNC_END_DRAIN();
    }
    // drain stray clamped stages before LDS goes out of scope at wave exit
    asm volatile("s_waitcnt vmcnt(0)" ::: "memory");

    // ---- epilogue: C/D layout col = lane&15, row = (lane>>4)*4 + reg ----
    const int crow = (lane >> 4) * 4, ccol = lane & 15;
#pragma unroll
    for (int i = 0; i < 8; i++)
#pragma unroll
        for (int j = 0; j < NF; j++) {
            const int col = bn + wn + j * 16 + ccol;
            const int rowb = bm + wm + i * 16 + crow;
            size_t basec = (size_t)rowb * N + col;
            if (EPI == 0) {
#pragma unroll
                for (int r = 0; r < 4; r++)
                    Cf[basec + (size_t)r * N] = acc[i][j][r];
            } else {
                // cols [0,2048) are q|k: RoPE. 16-col tile never straddles the
                // 2048 boundary or a 128 head boundary -> wave-uniform branch.
                const bool qk = col < 2048;
                const int fi = (col & 127) >> 1;
                const bool even = (col & 1) == 0;
                uint32_t* Cd = (uint32_t*)(Cb + ((size_t)rowb * N + (col & ~1)));
#pragma unroll
                for (int r = 0; r < 4; r++) {
                    float v = acc[i][j][r];
                    if (qk) {
                        int s = (rowb + r) & (S_ - 1);
                        float2 cs = ctab[s * 64 + fi];
                        float pp = __shfl_xor(v, 1);
                        v = even ? v * cs.x - pp * cs.y : v * cs.x + pp * cs.y;
                    }
                    int hb = (int)(unsigned short)f2bf(v);
                    int pb = __shfl_xor(hb, 1);
                    if (even)
                        Cd[(size_t)r * (N >> 1)] = (uint32_t)(hb | (pb << 16));
                }
            }
        }
}

// ---------------- sliding-window attn + gate + silu(z) + RMSNorm -> yn bf16 ----------------
__global__ __launch_bounds__(256) void k_attn(const unsigned short* __restrict__ qkvz,
                                              const float* __restrict__ bgag,
                                              const float* __restrict__ norm_w,
                                              short* __restrict__ yn) {
    const int m = blockIdx.x;
    const int s = m & (S_ - 1);
    const int t = threadIdx.x;
    __shared__ unsigned short kvls[5][2048];  // rows m-off, cols [1024,3072) = k|v
    __shared__ unsigned short qzls[2048];     // [0,1024)=q row m, [1024,2048)=z row m
    __shared__ float sc[NH_][5];
    __shared__ float red[4];
    const int nOff = (s < 4 ? s : 4) + 1;

    for (int off = 0; off < 5; off++) {
        if (off < nOff) {
            const ushort4* r = (const ushort4*)(qkvz + (size_t)(m - off) * NQKVZ + 1024);
            ushort4* d = (ushort4*)kvls[off];
            d[t] = r[t];
            d[t + 256] = r[t + 256];
        }
    }
    {
        const unsigned short* r = qkvz + (size_t)m * NQKVZ;
        ushort4* d = (ushort4*)qzls;
        d[t] = ((const ushort4*)r)[t];                    // q
        d[256 + t] = ((const ushort4*)(r + 3072))[t];     // z
    }
    __syncthreads();

    // scores: 8 heads x 32 lanes each; each lane covers 4 d's
    {
        const int h = t >> 5, l = t & 31;
        float qv[4];
#pragma unroll
        for (int d = 0; d < 4; d++) qv[d] = bf2f(qzls[h * 128 + l * 4 + d]);
        const float ag = bgag[(size_t)m * 16 + 8 + h];
#pragma unroll
        for (int off = 0; off < 5; off++) {
            float acc = 0.f;
            if (off < nOff) {
#pragma unroll
                for (int d = 0; d < 4; d++)
                    acc += qv[d] * bf2f(kvls[off][h * 128 + l * 4 + d]);
            }
#pragma unroll
            for (int w = 1; w < 32; w <<= 1) acc += __shfl_xor(acc, w);
            if (l == 0) {
                float val = 0.f;
                if (off < nOff) {
                    float bg = bgag[(size_t)(m - off) * 16 + h];
                    float g = 1.f / (1.f + expf(-ag * bg));
                    val = acc * 0.08838834764831845f * g;   // 1/sqrt(128) * gate
                }
                sc[h][off] = val;
            }
        }
    }
    __syncthreads();

    // phase 2: 4 consecutive elements per thread
    const int e0 = t * 4, h = e0 >> 7;
    float o[4] = {0.f, 0.f, 0.f, 0.f};
    if (s == 0) {
#pragma unroll
        for (int d = 0; d < 4; d++) o[d] = bf2f(kvls[0][1024 + e0 + d]);
    } else {
        for (int off = 0; off < nOff; off++) {
            float w = sc[h][off];
#pragma unroll
            for (int d = 0; d < 4; d++) o[d] += w * bf2f(kvls[off][1024 + e0 + d]);
        }
    }
    float y[4], zs4[4], ss = 0.f;
#pragma unroll
    for (int d = 0; d < 4; d++) {
        float z = bf2f(qzls[1024 + e0 + d]);
        float sg = 1.f / (1.f + expf(-z));
        y[d] = o[d] * sg;
        zs4[d] = z * sg;
        ss += y[d] * y[d];
    }
    const int wave = t >> 6, lane = t & 63;
#pragma unroll
    for (int w = 1; w < 64; w <<= 1) ss += __shfl_xor(ss, w);
    if (lane == 0) red[wave] = ss;
    __syncthreads();
    float tot = red[0] + red[1] + red[2] + red[3];
    float rinv = 1.f / sqrtf(tot * (1.0f / 1024.0f) + 1e-6f);
    short4 ov;
    ov.x = f2bf(y[0] * rinv * norm_w[e0 + 0] * zs4[0]);
    ov.y = f2bf(y[1] * rinv * norm_w[e0 + 1] * zs4[1]);
    ov.z = f2bf(y[2] * rinv * norm_w[e0 + 2] * zs4[2]);
    ov.w = f2bf(y[3] * rinv * norm_w[e0 + 3] * zs4[3]);
    ((short4*)yn)[(size_t)m * 256 + t] = ov;
}

extern "C" void kernel_launch(void* const* d_in, const int* in_sizes, int n_in,
                              void* d_out, int out_size, void* d_ws, size_t ws_size,
                              hipStream_t stream) {
    const float* x      = (const float*)d_in[0];
    const float* W_qkv  = (const float*)d_in[1];
    const float* W_z    = (const float*)d_in[2];
    const float* W_b    = (const float*)d_in[3];
    const float* W_a    = (const float*)d_in[4];
    const float* norm_w = (const float*)d_in[5];
    const float* W_out  = (const float*)d_in[6];
    float* out = (float*)d_out;

    // workspace (~135 MB)
    char* ws = (char*)d_ws;
    short* xb    = (short*)ws;          ws += (size_t)MR * H_ * 2;       // 32 MB
    short* Wt1   = (short*)ws;          ws += (size_t)NQKVZ * H_ * 2;    // 16 MB
    short* Wt2   = (short*)ws;          ws += (size_t)H_ * KD_ * 2;      //  4 MB
    unsigned short* qkvzb = (unsigned short*)ws; ws += (size_t)MR * NQKVZ * 2; // 64 MB
    float* bgag  = (float*)ws;          ws += (size_t)MR * 16 * 4;       // 0.5 MB
    short* yn    = (short*)ws;          ws += (size_t)MR * KD_ * 2;      // 16 MB
    float2* ctab = (float2*)ws;         ws += (size_t)S_ * 64 * 8;       //  2 MB

    // 1. fused convert x->bf16 + bg/ag skinny GEMM (single pass over x)
    k_cvt_bgag<<<MR, 256, 0, stream>>>(x, xb, W_b, W_a, bgag);
    // 2. transpose-convert weights
    k_transpose_cvt<<<dim3(3072 / 32, 2048 / 32), dim3(32, 8), 0, stream>>>(W_qkv, Wt1, 2048, 3072);
    k_transpose_cvt<<<dim3(1024 / 32, 2048 / 32), dim3(32, 8), 0, stream>>>(W_z, Wt1 + (size_t)3072 * 2048, 2048, 1024);
    k_transpose_cvt<<<dim3(2048 / 32, 1024 / 32), dim3(32, 8), 0, stream>>>(W_out, Wt2, 1024, 2048);
    // 3. rope table
    k_ropetab<<<S_ * 64 / 256, 256, 0, stream>>>(ctab);
    // 4. GEMM1 (2-phase 256², fused rope epilogue): qkvz = rope(x @ [W_qkv|W_z])
    k_gemm256<256, 1><<<(MR / 256) * (NQKVZ / 256), 512, 0, stream>>>(
        xb, Wt1, nullptr, qkvzb, ctab, MR, NQKVZ, H_);
    // 5. attention window + gating + RMSNorm -> yn (bf16)
    k_attn<<<MR, 256, 0, stream>>>(qkvzb, bgag, norm_w, yn);
    // 6. GEMM2 (2-phase 256x256, 1 grid round): out = yn @ W_out
    k_gemm256<256, 0><<<(MR / 256) * (H_ / 256), 512, 0, stream>>>(
        yn, Wt2, out, nullptr, nullptr, MR, H_, KD_);
}

// Round 4
// 471.368 us; speedup vs baseline: 1.0051x; 1.0051x over previous
//
#include <hip/hip_runtime.h>
#include <hip/hip_bf16.h>
#include <stdint.h>

#define B_   2
#define S_   4096
#define H_   2048
#define NH_  8
#define D_   128
#define KD_  1024
#define MR   (B_ * S_)          // 8192 rows
#define NQKVZ 4096              // q|k|v|z concatenated width

typedef __attribute__((ext_vector_type(8))) short bf16x8;
typedef __attribute__((ext_vector_type(4))) float f32x4;

__device__ __forceinline__ short f2bf(float f) {
    union { float f; uint32_t u; } v; v.f = f;
    uint32_t r = v.u + 0x7FFF + ((v.u >> 16) & 1);   // RNE
    return (short)(r >> 16);
}
__device__ __forceinline__ float bf2f(unsigned short u) {
    union { uint32_t u; float f; } v; v.u = (uint32_t)u << 16; return v.f;
}

__device__ __forceinline__ void async_ld16(const void* g, void* l) {
    __builtin_amdgcn_global_load_lds(
        (const __attribute__((address_space(1))) uint32_t*)g,
        (__attribute__((address_space(3))) uint32_t*)l, 16, 0, 0);
}

// ---------------- fused: x row -> bf16 + bgag skinny GEMM ----------------
__global__ __launch_bounds__(256) void k_cvt_bgag(const float* __restrict__ x,
                                                  short* __restrict__ xb,
                                                  const float* __restrict__ Wb,
                                                  const float* __restrict__ Wa,
                                                  float* __restrict__ bgag) {
    const int m = blockIdx.x, t = threadIdx.x;
    __shared__ float xs[2048];
    __shared__ float part[256];
    const float4* xr = (const float4*)(x + (size_t)m * H_);
    float4 a = xr[t], b = xr[t + 256];
    ((float4*)xs)[t] = a;
    ((float4*)xs)[t + 256] = b;
    short4 oa, ob;
    oa.x = f2bf(a.x); oa.y = f2bf(a.y); oa.z = f2bf(a.z); oa.w = f2bf(a.w);
    ob.x = f2bf(b.x); ob.y = f2bf(b.y); ob.z = f2bf(b.z); ob.w = f2bf(b.w);
    short4* xo = (short4*)(xb + (size_t)m * H_);
    xo[t] = oa;
    xo[t + 256] = ob;
    __syncthreads();
    int col = t & 15, seg = t >> 4;
    const float* W = (col < 8) ? Wb : Wa;
    int c = col & 7;
    float acc = 0.f;
    int kb = seg * 128;
    for (int k = 0; k < 128; k++) acc += xs[kb + k] * W[(size_t)(kb + k) * 8 + c];
    part[t] = acc;
    __syncthreads();
    if (t < 16) {
        float s = 0.f;
        for (int j = 0; j < 16; j++) s += part[j * 16 + t];
        bgag[(size_t)m * 16 + t] = s;   // [0..8)=bg, [8..16)=ag
    }
}

// ---------------- transpose + convert: W (KxN f32) -> Wt (NxK bf16) ----------------
__global__ __launch_bounds__(256) void k_transpose_cvt(const float* __restrict__ W,
                                                       short* __restrict__ Wt,
                                                       int K, int N) {
    __shared__ float tile[32][33];
    int n0 = blockIdx.x * 32, k0 = blockIdx.y * 32;
    int tx = threadIdx.x, ty = threadIdx.y;   // 32 x 8
#pragma unroll
    for (int i = 0; i < 32; i += 8)
        tile[ty + i][tx] = W[(size_t)(k0 + ty + i) * N + n0 + tx];
    __syncthreads();
#pragma unroll
    for (int i = 0; i < 32; i += 8)
        Wt[(size_t)(n0 + ty + i) * K + k0 + tx] = f2bf(tile[tx][ty + i]);
}

// ---------------- RoPE table: ctab[s][i] = {cos(s*inv_i), sin(s*inv_i)} ----------------
__global__ __launch_bounds__(256) void k_ropetab(float2* __restrict__ ctab) {
    int idx = blockIdx.x * 256 + threadIdx.x;   // S_*64
    int i = idx & 63, s = idx >> 6;
    float inv = exp2f(-(float)i * (2.0f / 128.0f) * 19.931568569324174f);
    float f = (float)s * inv;
    float sn, cs;
    sincosf(f, &sn, &cs);
    ctab[idx] = make_float2(cs, sn);
}

// ====== 256x256 MFMA GEMM — 2 phases/K-tile, compiler-scheduled lgkm (R4) ======
// C = A(MxK bf16) * Bt(NxK bf16)^T.  BM=256, BK=64, 8 waves (2M x 4N),
// double-buffered LDS, counted vmcnt, XOR-swizzled chunks.
// R4: removed the forced lgkmcnt(0)+sched_barrier BEFORE the MFMA cluster.
// R1-R3 showed MfmaUtil pinned at 31% with vmem depth, phase count and bank
// conflicts all exonerated: the per-phase full-drain serialized the LDS pipe
// (~1000 cyc per K-tile: 192 b128 reads + 64KB DMA writes per CU) against the
// matrix pipes (~620 cyc). Now plain ds_reads + register deps let the
// compiler emit counted lgkmcnt so reads drain UNDER the MFMA cluster.
// Safety: a trailing lgkmcnt(0) before the single phase-end barrier
// guarantees all reads of this phase complete before any wave can issue the
// next phase's DMA stages (WAR on LDS regions). One barrier per phase.
// Race ledger (unchanged from R3):
//   S_A(kt) = (kt+1,kh1)->buf[p^1].kh1 ; S_B(kt) = (kt+2,kh0)->buf[p].kh0
//   reads phase A(kt): buf[p].kh0  (staged S_B(kt-2), >=2 drains old)
//   reads phase B(kt): buf[p].kh1  (staged S_A(kt-1), covered by vmcnt(8)
//     at end of A(kt): in-flight = S_A(kt)+S_B(kt-1) = 8 instrs exactly)
//   WAR: stage region readers are in the PREVIOUS phase; their reads are
//     complete before that phase's end barrier (trailing lgkmcnt(0)). ✓
// EPI=0: f32 C stores. EPI=1: fused RoPE on cols<2048, packed bf16 stores.
#define PHASE_TAIL() \
    __builtin_amdgcn_s_setprio(0); \
    asm volatile("s_waitcnt vmcnt(%0)" :: "n"(2 * (2 + LB)) : "memory"); \
    asm volatile("s_waitcnt lgkmcnt(0)" ::: "memory"); \
    asm volatile("s_barrier" ::: "memory")
#define LDA_ALL(KH) \
    _Pragma("unroll") for (int i = 0; i < 8; i++) \
        afr[i] = *(const bf16x8*)(base + (KH) * AHB + (wm + i * 16 + mrow) * 64 + kcA)
#define LDB_F(KH) \
    _Pragma("unroll") for (int j = 0; j < NF; j++) \
        bfr[j] = *(const bf16x8*)(base + 2 * AHB + (KH) * BHB + (wn + j * 16 + mrow) * 64 + kcA)
#define MFMA_ALL() \
    _Pragma("unroll") for (int i = 0; i < 8; i++) \
    _Pragma("unroll") for (int j = 0; j < NF; j++) \
        acc[i][j] = __builtin_amdgcn_mfma_f32_16x16x32_bf16(afr[i], bfr[j], acc[i][j], 0, 0, 0)

template <int BN, int EPI>
__global__ __launch_bounds__(512, 2) void k_gemm256(const short* __restrict__ A,
                                                    const short* __restrict__ Bt,
                                                    float* __restrict__ Cf,
                                                    unsigned short* __restrict__ Cb,
                                                    const float2* __restrict__ ctab,
                                                    int M, int N, int K) {
    constexpr int BM = 256;
    constexpr int NF = BN / 64;       // n-frags per wave
    constexpr int LB = BN / 128;      // B global_load_lds per half-tile per thread
    constexpr int AHB = BM * 64;      // bytes per A kh-half (256 rows x 32 bf16)
    constexpr int BHB = BN * 64;
    constexpr int BUFB = 2 * AHB + 2 * BHB;
    __shared__ __align__(16) char lds[2 * BUFB];

    const int t = threadIdx.x;
    const int lane = t & 63, wave = t >> 6;
    const int mrow = lane & 15;
    // read-side swizzle: chunk kc_lds = kc_global ^ ((row>>1)&3); row base is
    // a multiple of 16 so f(row) reduces to (mrow>>1)&3 (lane-constant).
    const int kcA = (((lane >> 4) ^ ((mrow >> 1) & 3)) * 16);

    // XCD-aware bijective swizzle (grid % 8 == 0 for both call sites).
    // bn varies FASTEST within an XCD chunk (B-panels co-resident in L2).
    const int nwg = gridDim.x;
    const int w0 = blockIdx.x;
    const int wg = (w0 & 7) * (nwg >> 3) + (w0 >> 3);
    const int NB = N / BN;
    const int bn = (wg % NB) * BN;
    const int bm = (wg / NB) * BM;

    const int wm = (wave >> 2) * 128;
    const int wn = (wave & 3) * (BN / 4);

    const short* __restrict__ Ab = A + (size_t)bm * K;
    const short* __restrict__ Bb = Bt + (size_t)bn * K;

    // per-thread stage offsets: chunk c -> (row=c>>2, kc=c&3); global source
    // uses kc ^ ((row>>1)&3) so that linear LDS + swizzled read = identity.
    int aoff[2], adst[2];
#pragma unroll
    for (int l = 0; l < 2; l++) {
        int c = t + l * 512;
        int row = c >> 2;
        int kcg = (c & 3) ^ ((row >> 1) & 3);
        aoff[l] = row * K + kcg * 8;
        adst[l] = c * 16;
    }
    int boff[LB], bdst[LB];
#pragma unroll
    for (int l = 0; l < LB; l++) {
        int c = t + l * 512;
        int row = c >> 2;
        int kcg = (c & 3) ^ ((row >> 1) & 3);
        boff[l] = row * K + kcg * 8;
        bdst[l] = c * 16;
    }

    const int NT = K >> 6;

    auto stageA = [&](int kt, int kh, int p) {
        const short* g = Ab + kt * 64 + kh * 32;
        char* d = lds + p * BUFB + kh * AHB;
#pragma unroll
        for (int l = 0; l < 2; l++) async_ld16(g + aoff[l], d + adst[l]);
    };
    auto stageB = [&](int kt, int kh, int p) {
        const short* g = Bb + kt * 64 + kh * 32;
        char* d = lds + p * BUFB + 2 * AHB + kh * BHB;
#pragma unroll
        for (int l = 0; l < LB; l++) async_ld16(g + boff[l], d + bdst[l]);
    };

    f32x4 acc[8][NF] = {};

    // ---- prologue: 3 half-pair groups in flight (12 instrs) ----
    stageA(0, 0, 0); stageB(0, 0, 0);      // group 1: (0,kh0)
    stageA(0, 1, 0); stageB(0, 1, 0);      // group 2: (0,kh1)
    {
        int k1 = (NT > 1) ? 1 : 0;
        stageA(k1, 0, 1); stageB(k1, 0, 1); // group 3: (1,kh0)
    }
    // drain group 1 only; leave 2 groups (8 instrs) in flight
    asm volatile("s_waitcnt vmcnt(%0)" :: "n"(2 * (2 + LB)) : "memory");
    asm volatile("s_barrier" ::: "memory");

    // ---- main loop: 2 phases per K-tile, ONE barrier per phase ----
    for (int kt = 0; kt < NT; kt++) {
        const int p = kt & 1;
        const char* base = lds + p * BUFB;
        const int k1 = (kt + 1 < NT) ? (kt + 1) : (NT - 1);
        const int k2 = (kt + 2 < NT) ? (kt + 2) : (NT - 1);
        bf16x8 afr[8], bfr[NF];

        // phase A: kh0 — reads + stage issued, MFMA overlaps read drain
        LDB_F(0);
        LDA_ALL(0);
        stageA(k1, 1, p ^ 1); stageB(k1, 1, p ^ 1);
        __builtin_amdgcn_s_setprio(1);
        MFMA_ALL();
        PHASE_TAIL();

        // phase B: kh1
        LDB_F(1);
        LDA_ALL(1);
        stageA(k2, 0, p); stageB(k2, 0, p);
        __builtin_amdgcn_s_setprio(1);
        MFMA_ALL();
        PHASE_TAIL();
    }
    // drain stray clamped stages before LDS goes out of scope at wave exit
    asm volatile("s_waitcnt vmcnt(0)" ::: "memory");

    // ---- epilogue: C/D layout col = lane&15, row = (lane>>4)*4 + reg ----
    const int crow = (lane >> 4) * 4, ccol = lane & 15;
#pragma unroll
    for (int i = 0; i < 8; i++)
#pragma unroll
        for (int j = 0; j < NF; j++) {
            const int col = bn + wn + j * 16 + ccol;
            const int rowb = bm + wm + i * 16 + crow;
            size_t basec = (size_t)rowb * N + col;
            if (EPI == 0) {
#pragma unroll
                for (int r = 0; r < 4; r++)
                    Cf[basec + (size_t)r * N] = acc[i][j][r];
            } else {
                // cols [0,2048) are q|k: RoPE. 16-col tile never straddles the
                // 2048 boundary or a 128 head boundary -> wave-uniform branch.
                const bool qk = col < 2048;
                const int fi = (col & 127) >> 1;
                const bool even = (col & 1) == 0;
                uint32_t* Cd = (uint32_t*)(Cb + ((size_t)rowb * N + (col & ~1)));
#pragma unroll
                for (int r = 0; r < 4; r++) {
                    float v = acc[i][j][r];
                    if (qk) {
                        int s = (rowb + r) & (S_ - 1);
                        float2 cs = ctab[s * 64 + fi];
                        float pp = __shfl_xor(v, 1);
                        v = even ? v * cs.x - pp * cs.y : v * cs.x + pp * cs.y;
                    }
                    int hb = (int)(unsigned short)f2bf(v);
                    int pb = __shfl_xor(hb, 1);
                    if (even)
                        Cd[(size_t)r * (N >> 1)] = (uint32_t)(hb | (pb << 16));
                }
            }
        }
}

// ---------------- sliding-window attn + gate + silu(z) + RMSNorm -> yn bf16 ----------------
__global__ __launch_bounds__(256) void k_attn(const unsigned short* __restrict__ qkvz,
                                              const float* __restrict__ bgag,
                                              const float* __restrict__ norm_w,
                                              short* __restrict__ yn) {
    const int m = blockIdx.x;
    const int s = m & (S_ - 1);
    const int t = threadIdx.x;
    __shared__ unsigned short kvls[5][2048];  // rows m-off, cols [1024,3072) = k|v
    __shared__ unsigned short qzls[2048];     // [0,1024)=q row m, [1024,2048)=z row m
    __shared__ float sc[NH_][5];
    __shared__ float red[4];
    const int nOff = (s < 4 ? s : 4) + 1;

    for (int off = 0; off < 5; off++) {
        if (off < nOff) {
            const ushort4* r = (const ushort4*)(qkvz + (size_t)(m - off) * NQKVZ + 1024);
            ushort4* d = (ushort4*)kvls[off];
            d[t] = r[t];
            d[t + 256] = r[t + 256];
        }
    }
    {
        const unsigned short* r = qkvz + (size_t)m * NQKVZ;
        ushort4* d = (ushort4*)qzls;
        d[t] = ((const ushort4*)r)[t];                    // q
        d[256 + t] = ((const ushort4*)(r + 3072))[t];     // z
    }
    __syncthreads();

    // scores: 8 heads x 32 lanes each; each lane covers 4 d's
    {
        const int h = t >> 5, l = t & 31;
        float qv[4];
#pragma unroll
        for (int d = 0; d < 4; d++) qv[d] = bf2f(qzls[h * 128 + l * 4 + d]);
        const float ag = bgag[(size_t)m * 16 + 8 + h];
#pragma unroll
        for (int off = 0; off < 5; off++) {
            float acc = 0.f;
            if (off < nOff) {
#pragma unroll
                for (int d = 0; d < 4; d++)
                    acc += qv[d] * bf2f(kvls[off][h * 128 + l * 4 + d]);
            }
#pragma unroll
            for (int w = 1; w < 32; w <<= 1) acc += __shfl_xor(acc, w);
            if (l == 0) {
                float val = 0.f;
                if (off < nOff) {
                    float bg = bgag[(size_t)(m - off) * 16 + h];
                    float g = 1.f / (1.f + expf(-ag * bg));
                    val = acc * 0.08838834764831845f * g;   // 1/sqrt(128) * gate
                }
                sc[h][off] = val;
            }
        }
    }
    __syncthreads();

    // phase 2: 4 consecutive elements per thread
    const int e0 = t * 4, h = e0 >> 7;
    float o[4] = {0.f, 0.f, 0.f, 0.f};
    if (s == 0) {
#pragma unroll
        for (int d = 0; d < 4; d++) o[d] = bf2f(kvls[0][1024 + e0 + d]);
    } else {
        for (int off = 0; off < nOff; off++) {
            float w = sc[h][off];
#pragma unroll
            for (int d = 0; d < 4; d++) o[d] += w * bf2f(kvls[off][1024 + e0 + d]);
        }
    }
    float y[4], zs4[4], ss = 0.f;
#pragma unroll
    for (int d = 0; d < 4; d++) {
        float z = bf2f(qzls[1024 + e0 + d]);
        float sg = 1.f / (1.f + expf(-z));
        y[d] = o[d] * sg;
        zs4[d] = z * sg;
        ss += y[d] * y[d];
    }
    const int wave = t >> 6, lane = t & 63;
#pragma unroll
    for (int w = 1; w < 64; w <<= 1) ss += __shfl_xor(ss, w);
    if (lane == 0) red[wave] = ss;
    __syncthreads();
    float tot = red[0] + red[1] + red[2] + red[3];
    float rinv = 1.f / sqrtf(tot * (1.0f / 1024.0f) + 1e-6f);
    short4 ov;
    ov.x = f2bf(y[0] * rinv * norm_w[e0 + 0] * zs4[0]);
    ov.y = f2bf(y[1] * rinv * norm_w[e0 + 1] * zs4[1]);
    ov.z = f2bf(y[2] * rinv * norm_w[e0 + 2] * zs4[2]);
    ov.w = f2bf(y[3] * rinv * norm_w[e0 + 3] * zs4[3]);
    ((short4*)yn)[(size_t)m * 256 + t] = ov;
}

extern "C" void kernel_launch(void* const* d_in, const int* in_sizes, int n_in,
                              void* d_out, int out_size, void* d_ws, size_t ws_size,
                              hipStream_t stream) {
    const float* x      = (const float*)d_in[0];
    const float* W_qkv  = (const float*)d_in[1];
    const float* W_z    = (const float*)d_in[2];
    const float* W_b    = (const float*)d_in[3];
    const float* W_a    = (const float*)d_in[4];
    const float* norm_w = (const float*)d_in[5];
    const float* W_out  = (const float*)d_in[6];
    float* out = (float*)d_out;

    // workspace (~135 MB)
    char* ws = (char*)d_ws;
    short* xb    = (short*)ws;          ws += (size_t)MR * H_ * 2;       // 32 MB
    short* Wt1   = (short*)ws;          ws += (size_t)NQKVZ * H_ * 2;    // 16 MB
    short* Wt2   = (short*)ws;          ws += (size_t)H_ * KD_ * 2;      //  4 MB
    unsigned short* qkvzb = (unsigned short*)ws; ws += (size_t)MR * NQKVZ * 2; // 64 MB
    float* bgag  = (float*)ws;          ws += (size_t)MR * 16 * 4;       // 0.5 MB
    short* yn    = (short*)ws;          ws += (size_t)MR * KD_ * 2;      // 16 MB
    float2* ctab = (float2*)ws;         ws += (size_t)S_ * 64 * 8;       //  2 MB

    // 1. fused convert x->bf16 + bg/ag skinny GEMM (single pass over x)
    k_cvt_bgag<<<MR, 256, 0, stream>>>(x, xb, W_b, W_a, bgag);
    // 2. transpose-convert weights
    k_transpose_cvt<<<dim3(3072 / 32, 2048 / 32), dim3(32, 8), 0, stream>>>(W_qkv, Wt1, 2048, 3072);
    k_transpose_cvt<<<dim3(1024 / 32, 2048 / 32), dim3(32, 8), 0, stream>>>(W_z, Wt1 + (size_t)3072 * 2048, 2048, 1024);
    k_transpose_cvt<<<dim3(2048 / 32, 1024 / 32), dim3(32, 8), 0, stream>>>(W_out, Wt2, 1024, 2048);
    // 3. rope table
    k_ropetab<<<S_ * 64 / 256, 256, 0, stream>>>(ctab);
    // 4. GEMM1 (2-phase 256², fused rope epilogue): qkvz = rope(x @ [W_qkv|W_z])
    k_gemm256<256, 1><<<(MR / 256) * (NQKVZ / 256), 512, 0, stream>>>(
        xb, Wt1, nullptr, qkvzb, ctab, MR, NQKVZ, H_);
    // 5. attention window + gating + RMSNorm -> yn (bf16)
    k_attn<<<MR, 256, 0, stream>>>(qkvzb, bgag, norm_w, yn);
    // 6. GEMM2 (2-phase 256x256, 1 grid round): out = yn @ W_out
    k_gemm256<256, 0><<<(MR / 256) * (H_ / 256), 512, 0, stream>>>(
        yn, Wt2, out, nullptr, nullptr, MR, H_, KD_);
}

// Round 5
// 471.044 us; speedup vs baseline: 1.0058x; 1.0007x over previous
//
#include <hip/hip_runtime.h>
#include <hip/hip_bf16.h>
#include <stdint.h>

#define B_   2
#define S_   4096
#define H_   2048
#define NH_  8
#define D_   128
#define KD_  1024
#define MR   (B_ * S_)          // 8192 rows
#define NQKVZ 4096              // q|k|v|z concatenated width

typedef __attribute__((ext_vector_type(8))) short bf16x8;
typedef __attribute__((ext_vector_type(4))) float f32x4;

__device__ __forceinline__ short f2bf(float f) {
    union { float f; uint32_t u; } v; v.f = f;
    uint32_t r = v.u + 0x7FFF + ((v.u >> 16) & 1);   // RNE
    return (short)(r >> 16);
}
__device__ __forceinline__ float bf2f(unsigned short u) {
    union { uint32_t u; float f; } v; v.u = (uint32_t)u << 16; return v.f;
}

__device__ __forceinline__ void async_ld16(const void* g, void* l) {
    __builtin_amdgcn_global_load_lds(
        (const __attribute__((address_space(1))) uint32_t*)g,
        (__attribute__((address_space(3))) uint32_t*)l, 16, 0, 0);
}

// ---------------- fused: x row -> bf16 + bgag skinny GEMM ----------------
__global__ __launch_bounds__(256) void k_cvt_bgag(const float* __restrict__ x,
                                                  short* __restrict__ xb,
                                                  const float* __restrict__ Wb,
                                                  const float* __restrict__ Wa,
                                                  float* __restrict__ bgag) {
    const int m = blockIdx.x, t = threadIdx.x;
    __shared__ float xs[2048];
    __shared__ float part[256];
    const float4* xr = (const float4*)(x + (size_t)m * H_);
    float4 a = xr[t], b = xr[t + 256];
    ((float4*)xs)[t] = a;
    ((float4*)xs)[t + 256] = b;
    short4 oa, ob;
    oa.x = f2bf(a.x); oa.y = f2bf(a.y); oa.z = f2bf(a.z); oa.w = f2bf(a.w);
    ob.x = f2bf(b.x); ob.y = f2bf(b.y); ob.z = f2bf(b.z); ob.w = f2bf(b.w);
    short4* xo = (short4*)(xb + (size_t)m * H_);
    xo[t] = oa;
    xo[t + 256] = ob;
    __syncthreads();
    int col = t & 15, seg = t >> 4;
    const float* W = (col < 8) ? Wb : Wa;
    int c = col & 7;
    float acc = 0.f;
    int kb = seg * 128;
    for (int k = 0; k < 128; k++) acc += xs[kb + k] * W[(size_t)(kb + k) * 8 + c];
    part[t] = acc;
    __syncthreads();
    if (t < 16) {
        float s = 0.f;
        for (int j = 0; j < 16; j++) s += part[j * 16 + t];
        bgag[(size_t)m * 16 + t] = s;   // [0..8)=bg, [8..16)=ag
    }
}

// ---------------- transpose + convert: W (KxN f32) -> Wt (NxK bf16) ----------------
__global__ __launch_bounds__(256) void k_transpose_cvt(const float* __restrict__ W,
                                                       short* __restrict__ Wt,
                                                       int K, int N) {
    __shared__ float tile[32][33];
    int n0 = blockIdx.x * 32, k0 = blockIdx.y * 32;
    int tx = threadIdx.x, ty = threadIdx.y;   // 32 x 8
#pragma unroll
    for (int i = 0; i < 32; i += 8)
        tile[ty + i][tx] = W[(size_t)(k0 + ty + i) * N + n0 + tx];
    __syncthreads();
#pragma unroll
    for (int i = 0; i < 32; i += 8)
        Wt[(size_t)(n0 + ty + i) * K + k0 + tx] = f2bf(tile[tx][ty + i]);
}

// ---------------- RoPE table: ctab[s][i] = {cos(s*inv_i), sin(s*inv_i)} ----------------
__global__ __launch_bounds__(256) void k_ropetab(float2* __restrict__ ctab) {
    int idx = blockIdx.x * 256 + threadIdx.x;   // S_*64
    int i = idx & 63, s = idx >> 6;
    float inv = exp2f(-(float)i * (2.0f / 128.0f) * 19.931568569324174f);
    float f = (float)s * inv;
    float sn, cs;
    sincosf(f, &sn, &cs);
    ctab[idx] = make_float2(cs, sn);
}

// ====== 256x256 MFMA GEMM — cross-phase fragment prefetch (R5) ======
// C = A(MxK bf16) * Bt(NxK bf16)^T.  BM=256, BK=64, 8 waves (2M x 4N),
// double-buffered LDS, counted vmcnt, XOR-swizzled chunks.
// R5: R1-R4 established MfmaUtil pinned at ~31% = LDS-read time serialized
// against MFMA time (per K-tile/CU: 256 KiB LDS traffic ~2000-3000 cyc vs
// 2483 cyc MFMA; operands were read IN the phase that consumed them ->
// register dependency serializes). Fix: fragment double-buffering across
// phases. Each phase: (a) reads afr[4..7] of the CURRENT region (drains
// under the first 16 MFMAs), (b) prefetches afr[0..3]+bfr of the NEXT
// phase's region, (c) stages DMA, then MFMAs on operands prefetched LAST
// phase. VGPR budget forces the partial scheme (afr03+bfr x2, afrS x1).
// Ledger (groups of 4 loads; phases: A(kt)=buf[p].kh0, B(kt)=buf[p].kh1):
//   stage at A(kt): (kt+1,kh1)->buf[p^1].kh1 ; at B(kt): (kt+2,kh0)->buf[p].kh0
//   vmcnt(4) at EVERY phase end (1 group in flight) => at phase ph, data of
//   phase ph+1 is drained + barrier-visible => prefetch is safe.
//   WAR: region overwritten at phase ph was last READ (prefetch) at ph-2,
//   consumed by MFMA at ph-1; reads complete before ph-1's MFMAs issue,
//   which precede the ph-1 end barrier < stage at ph.  Race-free.
// EPI=0: f32 C stores. EPI=1: fused RoPE on cols<2048, packed bf16 stores.
#define PHASE_TAIL() \
    __builtin_amdgcn_s_setprio(0); \
    asm volatile("s_waitcnt vmcnt(%0)" :: "n"(2 + LB) : "memory"); \
    asm volatile("s_barrier" ::: "memory")
#define LDB_P(SET, BASE, KH) \
    _Pragma("unroll") for (int j = 0; j < NF; j++) \
        bf##SET[j] = *(const bf16x8*)((BASE) + 2 * AHB + (KH) * BHB + (wn + j * 16 + mrow) * 64 + kcA)
#define LDA03_P(SET, BASE, KH) \
    _Pragma("unroll") for (int i = 0; i < 4; i++) \
        af##SET[i] = *(const bf16x8*)((BASE) + (KH) * AHB + (wm + i * 16 + mrow) * 64 + kcA)
#define LDA47_S(BASE, KH) \
    _Pragma("unroll") for (int i = 0; i < 4; i++) \
        afS[i] = *(const bf16x8*)((BASE) + (KH) * AHB + (wm + 64 + i * 16 + mrow) * 64 + kcA)
#define MFMA_PH(SET) \
    _Pragma("unroll") for (int i = 0; i < 4; i++) \
    _Pragma("unroll") for (int j = 0; j < NF; j++) \
        acc[i][j] = __builtin_amdgcn_mfma_f32_16x16x32_bf16(af##SET[i], bf##SET[j], acc[i][j], 0, 0, 0); \
    _Pragma("unroll") for (int i = 0; i < 4; i++) \
    _Pragma("unroll") for (int j = 0; j < NF; j++) \
        acc[4 + i][j] = __builtin_amdgcn_mfma_f32_16x16x32_bf16(afS[i], bf##SET[j], acc[4 + i][j], 0, 0, 0)

template <int BN, int EPI>
__global__ __launch_bounds__(512, 2) void k_gemm256(const short* __restrict__ A,
                                                    const short* __restrict__ Bt,
                                                    float* __restrict__ Cf,
                                                    unsigned short* __restrict__ Cb,
                                                    const float2* __restrict__ ctab,
                                                    int M, int N, int K) {
    constexpr int BM = 256;
    constexpr int NF = BN / 64;       // n-frags per wave
    constexpr int LB = BN / 128;      // B global_load_lds per half-tile per thread
    constexpr int AHB = BM * 64;      // bytes per A kh-half (256 rows x 32 bf16)
    constexpr int BHB = BN * 64;
    constexpr int BUFB = 2 * AHB + 2 * BHB;
    __shared__ __align__(16) char lds[2 * BUFB];

    const int t = threadIdx.x;
    const int lane = t & 63, wave = t >> 6;
    const int mrow = lane & 15;
    // read-side swizzle: chunk kc_lds = kc_global ^ ((row>>1)&3); row base is
    // a multiple of 16 so f(row) reduces to (mrow>>1)&3 (lane-constant).
    const int kcA = (((lane >> 4) ^ ((mrow >> 1) & 3)) * 16);

    // XCD-aware bijective swizzle (grid % 8 == 0 for both call sites).
    // bn varies FASTEST within an XCD chunk (B-panels co-resident in L2).
    const int nwg = gridDim.x;
    const int w0 = blockIdx.x;
    const int wg = (w0 & 7) * (nwg >> 3) + (w0 >> 3);
    const int NB = N / BN;
    const int bn = (wg % NB) * BN;
    const int bm = (wg / NB) * BM;

    const int wm = (wave >> 2) * 128;
    const int wn = (wave & 3) * (BN / 4);

    const short* __restrict__ Ab = A + (size_t)bm * K;
    const short* __restrict__ Bb = Bt + (size_t)bn * K;

    // per-thread stage offsets: chunk c -> (row=c>>2, kc=c&3); global source
    // uses kc ^ ((row>>1)&3) so that linear LDS + swizzled read = identity.
    int aoff[2], adst[2];
#pragma unroll
    for (int l = 0; l < 2; l++) {
        int c = t + l * 512;
        int row = c >> 2;
        int kcg = (c & 3) ^ ((row >> 1) & 3);
        aoff[l] = row * K + kcg * 8;
        adst[l] = c * 16;
    }
    int boff[LB], bdst[LB];
#pragma unroll
    for (int l = 0; l < LB; l++) {
        int c = t + l * 512;
        int row = c >> 2;
        int kcg = (c & 3) ^ ((row >> 1) & 3);
        boff[l] = row * K + kcg * 8;
        bdst[l] = c * 16;
    }

    const int NT = K >> 6;

    auto stageA = [&](int kt, int kh, int p) {
        const short* g = Ab + kt * 64 + kh * 32;
        char* d = lds + p * BUFB + kh * AHB;
#pragma unroll
        for (int l = 0; l < 2; l++) async_ld16(g + aoff[l], d + adst[l]);
    };
    auto stageB = [&](int kt, int kh, int p) {
        const short* g = Bb + kt * 64 + kh * 32;
        char* d = lds + p * BUFB + 2 * AHB + kh * BHB;
#pragma unroll
        for (int l = 0; l < LB; l++) async_ld16(g + boff[l], d + bdst[l]);
    };

    f32x4 acc[8][NF] = {};
    bf16x8 afE[4], bfE[NF], afO[4], bfO[NF], afS[4];

    // ---- prologue: 3 half-pair groups in flight, prefetch E from (0,kh0) ----
    stageA(0, 0, 0); stageB(0, 0, 0);      // group 1: (0,kh0)
    stageA(0, 1, 0); stageB(0, 1, 0);      // group 2: (0,kh1)
    {
        int k1 = (NT > 1) ? 1 : 0;
        stageA(k1, 0, 1); stageB(k1, 0, 1); // group 3: (1,kh0)
    }
    asm volatile("s_waitcnt vmcnt(%0)" :: "n"(2 * (2 + LB)) : "memory"); // grp1 done
    asm volatile("s_barrier" ::: "memory");
    LDB_P(E, lds, 0); LDA03_P(E, lds, 0);  // fragments for phase A(0)
    asm volatile("s_waitcnt vmcnt(%0)" :: "n"(2 + LB) : "memory");        // grp2 done
    asm volatile("s_barrier" ::: "memory");

    // ---- main loop: 2 phases per K-tile, fragments prefetched 1 phase ahead ----
    for (int kt = 0; kt < NT; kt++) {
        const int p = kt & 1;
        const char* base = lds + p * BUFB;
        const char* baseN = lds + (p ^ 1) * BUFB;
        const int k1 = (kt + 1 < NT) ? (kt + 1) : (NT - 1);
        const int k2 = (kt + 2 < NT) ? (kt + 2) : (NT - 1);

        // phase A: MFMA on E (buf[p].kh0); in-phase afS; prefetch O <- buf[p].kh1
        LDA47_S(base, 0);
        LDB_P(O, base, 1); LDA03_P(O, base, 1);
        stageA(k1, 1, p ^ 1); stageB(k1, 1, p ^ 1);
        __builtin_amdgcn_sched_barrier(0);
        __builtin_amdgcn_s_setprio(1);
        MFMA_PH(E);
        PHASE_TAIL();

        // phase B: MFMA on O (buf[p].kh1); in-phase afS; prefetch E <- buf[p^1].kh0
        LDA47_S(base, 1);
        LDB_P(E, baseN, 0); LDA03_P(E, baseN, 0);
        stageA(k2, 0, p); stageB(k2, 0, p);
        __builtin_amdgcn_sched_barrier(0);
        __builtin_amdgcn_s_setprio(1);
        MFMA_PH(O);
        PHASE_TAIL();
    }
    // drain stray clamped stages before LDS goes out of scope at wave exit
    asm volatile("s_waitcnt vmcnt(0)" ::: "memory");

    // ---- epilogue: C/D layout col = lane&15, row = (lane>>4)*4 + reg ----
    const int crow = (lane >> 4) * 4, ccol = lane & 15;
#pragma unroll
    for (int i = 0; i < 8; i++)
#pragma unroll
        for (int j = 0; j < NF; j++) {
            const int col = bn + wn + j * 16 + ccol;
            const int rowb = bm + wm + i * 16 + crow;
            size_t basec = (size_t)rowb * N + col;
            if (EPI == 0) {
#pragma unroll
                for (int r = 0; r < 4; r++)
                    Cf[basec + (size_t)r * N] = acc[i][j][r];
            } else {
                // cols [0,2048) are q|k: RoPE. 16-col tile never straddles the
                // 2048 boundary or a 128 head boundary -> wave-uniform branch.
                const bool qk = col < 2048;
                const int fi = (col & 127) >> 1;
                const bool even = (col & 1) == 0;
                uint32_t* Cd = (uint32_t*)(Cb + ((size_t)rowb * N + (col & ~1)));
#pragma unroll
                for (int r = 0; r < 4; r++) {
                    float v = acc[i][j][r];
                    if (qk) {
                        int s = (rowb + r) & (S_ - 1);
                        float2 cs = ctab[s * 64 + fi];
                        float pp = __shfl_xor(v, 1);
                        v = even ? v * cs.x - pp * cs.y : v * cs.x + pp * cs.y;
                    }
                    int hb = (int)(unsigned short)f2bf(v);
                    int pb = __shfl_xor(hb, 1);
                    if (even)
                        Cd[(size_t)r * (N >> 1)] = (uint32_t)(hb | (pb << 16));
                }
            }
        }
}

// ---------------- sliding-window attn + gate + silu(z) + RMSNorm -> yn bf16 ----------------
__global__ __launch_bounds__(256) void k_attn(const unsigned short* __restrict__ qkvz,
                                              const float* __restrict__ bgag,
                                              const float* __restrict__ norm_w,
                                              short* __restrict__ yn) {
    const int m = blockIdx.x;
    const int s = m & (S_ - 1);
    const int t = threadIdx.x;
    __shared__ unsigned short kvls[5][2048];  // rows m-off, cols [1024,3072) = k|v
    __shared__ unsigned short qzls[2048];     // [0,1024)=q row m, [1024,2048)=z row m
    __shared__ float sc[NH_][5];
    __shared__ float red[4];
    const int nOff = (s < 4 ? s : 4) + 1;

    for (int off = 0; off < 5; off++) {
        if (off < nOff) {
            const ushort4* r = (const ushort4*)(qkvz + (size_t)(m - off) * NQKVZ + 1024);
            ushort4* d = (ushort4*)kvls[off];
            d[t] = r[t];
            d[t + 256] = r[t + 256];
        }
    }
    {
        const unsigned short* r = qkvz + (size_t)m * NQKVZ;
        ushort4* d = (ushort4*)qzls;
        d[t] = ((const ushort4*)r)[t];                    // q
        d[256 + t] = ((const ushort4*)(r + 3072))[t];     // z
    }
    __syncthreads();

    // scores: 8 heads x 32 lanes each; each lane covers 4 d's
    {
        const int h = t >> 5, l = t & 31;
        float qv[4];
#pragma unroll
        for (int d = 0; d < 4; d++) qv[d] = bf2f(qzls[h * 128 + l * 4 + d]);
        const float ag = bgag[(size_t)m * 16 + 8 + h];
#pragma unroll
        for (int off = 0; off < 5; off++) {
            float acc = 0.f;
            if (off < nOff) {
#pragma unroll
                for (int d = 0; d < 4; d++)
                    acc += qv[d] * bf2f(kvls[off][h * 128 + l * 4 + d]);
            }
#pragma unroll
            for (int w = 1; w < 32; w <<= 1) acc += __shfl_xor(acc, w);
            if (l == 0) {
                float val = 0.f;
                if (off < nOff) {
                    float bg = bgag[(size_t)(m - off) * 16 + h];
                    float g = 1.f / (1.f + expf(-ag * bg));
                    val = acc * 0.08838834764831845f * g;   // 1/sqrt(128) * gate
                }
                sc[h][off] = val;
            }
        }
    }
    __syncthreads();

    // phase 2: 4 consecutive elements per thread
    const int e0 = t * 4, h = e0 >> 7;
    float o[4] = {0.f, 0.f, 0.f, 0.f};
    if (s == 0) {
#pragma unroll
        for (int d = 0; d < 4; d++) o[d] = bf2f(kvls[0][1024 + e0 + d]);
    } else {
        for (int off = 0; off < nOff; off++) {
            float w = sc[h][off];
#pragma unroll
            for (int d = 0; d < 4; d++) o[d] += w * bf2f(kvls[off][1024 + e0 + d]);
        }
    }
    float y[4], zs4[4], ss = 0.f;
#pragma unroll
    for (int d = 0; d < 4; d++) {
        float z = bf2f(qzls[1024 + e0 + d]);
        float sg = 1.f / (1.f + expf(-z));
        y[d] = o[d] * sg;
        zs4[d] = z * sg;
        ss += y[d] * y[d];
    }
    const int wave = t >> 6, lane = t & 63;
#pragma unroll
    for (int w = 1; w < 64; w <<= 1) ss += __shfl_xor(ss, w);
    if (lane == 0) red[wave] = ss;
    __syncthreads();
    float tot = red[0] + red[1] + red[2] + red[3];
    float rinv = 1.f / sqrtf(tot * (1.0f / 1024.0f) + 1e-6f);
    short4 ov;
    ov.x = f2bf(y[0] * rinv * norm_w[e0 + 0] * zs4[0]);
    ov.y = f2bf(y[1] * rinv * norm_w[e0 + 1] * zs4[1]);
    ov.z = f2bf(y[2] * rinv * norm_w[e0 + 2] * zs4[2]);
    ov.w = f2bf(y[3] * rinv * norm_w[e0 + 3] * zs4[3]);
    ((short4*)yn)[(size_t)m * 256 + t] = ov;
}

extern "C" void kernel_launch(void* const* d_in, const int* in_sizes, int n_in,
                              void* d_out, int out_size, void* d_ws, size_t ws_size,
                              hipStream_t stream) {
    const float* x      = (const float*)d_in[0];
    const float* W_qkv  = (const float*)d_in[1];
    const float* W_z    = (const float*)d_in[2];
    const float* W_b    = (const float*)d_in[3];
    const float* W_a    = (const float*)d_in[4];
    const float* norm_w = (const float*)d_in[5];
    const float* W_out  = (const float*)d_in[6];
    float* out = (float*)d_out;

    // workspace (~135 MB)
    char* ws = (char*)d_ws;
    short* xb    = (short*)ws;          ws += (size_t)MR * H_ * 2;       // 32 MB
    short* Wt1   = (short*)ws;          ws += (size_t)NQKVZ * H_ * 2;    // 16 MB
    short* Wt2   = (short*)ws;          ws += (size_t)H_ * KD_ * 2;      //  4 MB
    unsigned short* qkvzb = (unsigned short*)ws; ws += (size_t)MR * NQKVZ * 2; // 64 MB
    float* bgag  = (float*)ws;          ws += (size_t)MR * 16 * 4;       // 0.5 MB
    short* yn    = (short*)ws;          ws += (size_t)MR * KD_ * 2;      // 16 MB
    float2* ctab = (float2*)ws;         ws += (size_t)S_ * 64 * 8;       //  2 MB

    // 1. fused convert x->bf16 + bg/ag skinny GEMM (single pass over x)
    k_cvt_bgag<<<MR, 256, 0, stream>>>(x, xb, W_b, W_a, bgag);
    // 2. transpose-convert weights
    k_transpose_cvt<<<dim3(3072 / 32, 2048 / 32), dim3(32, 8), 0, stream>>>(W_qkv, Wt1, 2048, 3072);
    k_transpose_cvt<<<dim3(1024 / 32, 2048 / 32), dim3(32, 8), 0, stream>>>(W_z, Wt1 + (size_t)3072 * 2048, 2048, 1024);
    k_transpose_cvt<<<dim3(2048 / 32, 1024 / 32), dim3(32, 8), 0, stream>>>(W_out, Wt2, 1024, 2048);
    // 3. rope table
    k_ropetab<<<S_ * 64 / 256, 256, 0, stream>>>(ctab);
    // 4. GEMM1 (frag-prefetch 256², fused rope epilogue): qkvz = rope(x @ [W_qkv|W_z])
    k_gemm256<256, 1><<<(MR / 256) * (NQKVZ / 256), 512, 0, stream>>>(
        xb, Wt1, nullptr, qkvzb, ctab, MR, NQKVZ, H_);
    // 5. attention window + gating + RMSNorm -> yn (bf16)
    k_attn<<<MR, 256, 0, stream>>>(qkvzb, bgag, norm_w, yn);
    // 6. GEMM2 (frag-prefetch 256x256, 1 grid round): out = yn @ W_out
    k_gemm256<256, 0><<<(MR / 256) * (H_ / 256), 512, 0, stream>>>(
        yn, Wt2, out, nullptr, nullptr, MR, H_, KD_);
}

// Round 6
// 450.893 us; speedup vs baseline: 1.0507x; 1.0447x over previous
//
#include <hip/hip_runtime.h>
#include <hip/hip_bf16.h>
#include <stdint.h>

#define B_   2
#define S_   4096
#define H_   2048
#define NH_  8
#define D_   128
#define KD_  1024
#define MR   (B_ * S_)          // 8192 rows
#define NQKVZ 4096              // q|k|v|z concatenated width

typedef __attribute__((ext_vector_type(8))) short bf16x8;
typedef __attribute__((ext_vector_type(4))) float f32x4;

__device__ __forceinline__ short f2bf(float f) {
    union { float f; uint32_t u; } v; v.f = f;
    uint32_t r = v.u + 0x7FFF + ((v.u >> 16) & 1);   // RNE
    return (short)(r >> 16);
}
__device__ __forceinline__ float bf2f(unsigned short u) {
    union { uint32_t u; float f; } v; v.u = (uint32_t)u << 16; return v.f;
}

__device__ __forceinline__ void async_ld16(const void* g, void* l) {
    __builtin_amdgcn_global_load_lds(
        (const __attribute__((address_space(1))) uint32_t*)g,
        (__attribute__((address_space(3))) uint32_t*)l, 16, 0, 0);
}

// ---------------- W_b|W_a -> transposed [16][2048] f32 (contiguous per col) ----------------
__global__ __launch_bounds__(256) void k_wba(const float* __restrict__ Wb,
                                             const float* __restrict__ Wa,
                                             float* __restrict__ Wba) {
    int idx = blockIdx.x * 256 + threadIdx.x;      // 16 * 2048
    int k = idx & 2047, c = idx >> 11;
    float v = (c < 8) ? Wb[(size_t)k * 8 + c] : Wa[(size_t)k * 8 + (c - 8)];
    Wba[(size_t)c * 2048 + k] = v;
}

// ---------------- fused: 4 x rows -> bf16 + bgag skinny GEMM (4x W reuse) ----------------
// R6: old version re-read 128 KB of W per ROW-block (1 GB L2 traffic total).
// 4 rows/block + transposed W => 256 MB traffic + contiguous float4 W reads.
__global__ __launch_bounds__(256) void k_cvt_bgag4(const float* __restrict__ x,
                                                   short* __restrict__ xb,
                                                   const float* __restrict__ Wba,
                                                   float* __restrict__ bgag) {
    const int m0 = blockIdx.x * 4, t = threadIdx.x;
    __shared__ float xs[4][2048];
    __shared__ float part[4][256];
#pragma unroll
    for (int rr = 0; rr < 4; rr++) {
        const float4* xr = (const float4*)(x + (size_t)(m0 + rr) * H_);
        float4 a = xr[t], b = xr[t + 256];
        ((float4*)xs[rr])[t] = a;
        ((float4*)xs[rr])[t + 256] = b;
        short4 oa, ob;
        oa.x = f2bf(a.x); oa.y = f2bf(a.y); oa.z = f2bf(a.z); oa.w = f2bf(a.w);
        ob.x = f2bf(b.x); ob.y = f2bf(b.y); ob.z = f2bf(b.z); ob.w = f2bf(b.w);
        short4* xo = (short4*)(xb + (size_t)(m0 + rr) * H_);
        xo[t] = oa;
        xo[t + 256] = ob;
    }
    __syncthreads();
    const int c = t & 15, seg = t >> 4;            // 16 cols x 16 k-segments
    const int kb = seg * 128;
    const float4* W4 = (const float4*)(Wba + (size_t)c * 2048 + kb);
    const float4* x0 = (const float4*)&xs[0][kb];
    const float4* x1 = (const float4*)&xs[1][kb];
    const float4* x2 = (const float4*)&xs[2][kb];
    const float4* x3 = (const float4*)&xs[3][kb];
    float a0 = 0.f, a1 = 0.f, a2 = 0.f, a3 = 0.f;
#pragma unroll 8
    for (int k4 = 0; k4 < 32; k4++) {
        float4 w = W4[k4];
        float4 v0 = x0[k4], v1 = x1[k4], v2 = x2[k4], v3 = x3[k4];
        a0 += w.x * v0.x + w.y * v0.y + w.z * v0.z + w.w * v0.w;
        a1 += w.x * v1.x + w.y * v1.y + w.z * v1.z + w.w * v1.w;
        a2 += w.x * v2.x + w.y * v2.y + w.z * v2.z + w.w * v2.w;
        a3 += w.x * v3.x + w.y * v3.y + w.z * v3.z + w.w * v3.w;
    }
    part[0][t] = a0; part[1][t] = a1; part[2][t] = a2; part[3][t] = a3;
    __syncthreads();
    if (t < 64) {
        int rr = t >> 4, cc = t & 15;
        float s = 0.f;
#pragma unroll
        for (int j = 0; j < 16; j++) s += part[rr][j * 16 + cc];
        bgag[(size_t)(m0 + rr) * 16 + cc] = s;   // [0..8)=bg, [8..16)=ag
    }
}

// ---------------- transpose + convert: W (KxN f32) -> Wt (NxK bf16) ----------------
__global__ __launch_bounds__(256) void k_transpose_cvt(const float* __restrict__ W,
                                                       short* __restrict__ Wt,
                                                       int K, int N) {
    __shared__ float tile[32][33];
    int n0 = blockIdx.x * 32, k0 = blockIdx.y * 32;
    int tx = threadIdx.x, ty = threadIdx.y;   // 32 x 8
#pragma unroll
    for (int i = 0; i < 32; i += 8)
        tile[ty + i][tx] = W[(size_t)(k0 + ty + i) * N + n0 + tx];
    __syncthreads();
#pragma unroll
    for (int i = 0; i < 32; i += 8)
        Wt[(size_t)(n0 + ty + i) * K + k0 + tx] = f2bf(tile[tx][ty + i]);
}

// ---------------- RoPE table: ctab[s][i] = {cos(s*inv_i), sin(s*inv_i)} ----------------
__global__ __launch_bounds__(256) void k_ropetab(float2* __restrict__ ctab) {
    int idx = blockIdx.x * 256 + threadIdx.x;   // S_*64
    int i = idx & 63, s = idx >> 6;
    float inv = exp2f(-(float)i * (2.0f / 128.0f) * 19.931568569324174f);
    float f = (float)s * inv;
    float sn, cs;
    sincosf(f, &sn, &cs);
    ctab[idx] = make_float2(cs, sn);
}

// ====== 256x256 MFMA GEMM — R5 K-loop (kept) + R6 coalesced EPI=0 epilogue ======
// C = A(MxK bf16) * Bt(NxK bf16)^T.  BM=256, BK=64, 8 waves (2M x 4N),
// double-buffered LDS, counted vmcnt, XOR-swizzled chunks, cross-phase
// fragment prefetch (R5). Ledger/race proofs: see R5 notes — unchanged.
// R6: EPI=0 epilogue stages C through the freed LDS ([128][260] f32 pad,
// <=2-way bank aliasing) -> fully coalesced float4 stores, replacing the
// 64-B-segment scattered f32 stores (4-row-strided lanes).
#define PHASE_TAIL() \
    __builtin_amdgcn_s_setprio(0); \
    asm volatile("s_waitcnt vmcnt(%0)" :: "n"(2 + LB) : "memory"); \
    asm volatile("s_barrier" ::: "memory")
#define LDB_P(SET, BASE, KH) \
    _Pragma("unroll") for (int j = 0; j < NF; j++) \
        bf##SET[j] = *(const bf16x8*)((BASE) + 2 * AHB + (KH) * BHB + (wn + j * 16 + mrow) * 64 + kcA)
#define LDA03_P(SET, BASE, KH) \
    _Pragma("unroll") for (int i = 0; i < 4; i++) \
        af##SET[i] = *(const bf16x8*)((BASE) + (KH) * AHB + (wm + i * 16 + mrow) * 64 + kcA)
#define LDA47_S(BASE, KH) \
    _Pragma("unroll") for (int i = 0; i < 4; i++) \
        afS[i] = *(const bf16x8*)((BASE) + (KH) * AHB + (wm + 64 + i * 16 + mrow) * 64 + kcA)
#define MFMA_PH(SET) \
    _Pragma("unroll") for (int i = 0; i < 4; i++) \
    _Pragma("unroll") for (int j = 0; j < NF; j++) \
        acc[i][j] = __builtin_amdgcn_mfma_f32_16x16x32_bf16(af##SET[i], bf##SET[j], acc[i][j], 0, 0, 0); \
    _Pragma("unroll") for (int i = 0; i < 4; i++) \
    _Pragma("unroll") for (int j = 0; j < NF; j++) \
        acc[4 + i][j] = __builtin_amdgcn_mfma_f32_16x16x32_bf16(afS[i], bf##SET[j], acc[4 + i][j], 0, 0, 0)

template <int BN, int EPI>
__global__ __launch_bounds__(512, 2) void k_gemm256(const short* __restrict__ A,
                                                    const short* __restrict__ Bt,
                                                    float* __restrict__ Cf,
                                                    unsigned short* __restrict__ Cb,
                                                    const float2* __restrict__ ctab,
                                                    int M, int N, int K) {
    constexpr int BM = 256;
    constexpr int NF = BN / 64;       // n-frags per wave
    constexpr int LB = BN / 128;      // B global_load_lds per half-tile per thread
    constexpr int AHB = BM * 64;      // bytes per A kh-half (256 rows x 32 bf16)
    constexpr int BHB = BN * 64;
    constexpr int BUFB = 2 * AHB + 2 * BHB;
    // EPI=0 additionally needs 128*260*4 = 133120 B for the C-stage (>= 2*BUFB)
    constexpr int LDSB = (EPI == 0) ? 133120 : 2 * BUFB;
    __shared__ __align__(16) char lds[LDSB];

    const int t = threadIdx.x;
    const int lane = t & 63, wave = t >> 6;
    const int mrow = lane & 15;
    // read-side swizzle: chunk kc_lds = kc_global ^ ((row>>1)&3); row base is
    // a multiple of 16 so f(row) reduces to (mrow>>1)&3 (lane-constant).
    const int kcA = (((lane >> 4) ^ ((mrow >> 1) & 3)) * 16);

    // XCD-aware bijective swizzle (grid % 8 == 0 for both call sites).
    // bn varies FASTEST within an XCD chunk (B-panels co-resident in L2).
    const int nwg = gridDim.x;
    const int w0 = blockIdx.x;
    const int wg = (w0 & 7) * (nwg >> 3) + (w0 >> 3);
    const int NB = N / BN;
    const int bn = (wg % NB) * BN;
    const int bm = (wg / NB) * BM;

    const int wm = (wave >> 2) * 128;
    const int wn = (wave & 3) * (BN / 4);

    const short* __restrict__ Ab = A + (size_t)bm * K;
    const short* __restrict__ Bb = Bt + (size_t)bn * K;

    // per-thread stage offsets: chunk c -> (row=c>>2, kc=c&3); global source
    // uses kc ^ ((row>>1)&3) so that linear LDS + swizzled read = identity.
    int aoff[2], adst[2];
#pragma unroll
    for (int l = 0; l < 2; l++) {
        int c = t + l * 512;
        int row = c >> 2;
        int kcg = (c & 3) ^ ((row >> 1) & 3);
        aoff[l] = row * K + kcg * 8;
        adst[l] = c * 16;
    }
    int boff[LB], bdst[LB];
#pragma unroll
    for (int l = 0; l < LB; l++) {
        int c = t + l * 512;
        int row = c >> 2;
        int kcg = (c & 3) ^ ((row >> 1) & 3);
        boff[l] = row * K + kcg * 8;
        bdst[l] = c * 16;
    }

    const int NT = K >> 6;

    auto stageA = [&](int kt, int kh, int p) {
        const short* g = Ab + kt * 64 + kh * 32;
        char* d = lds + p * BUFB + kh * AHB;
#pragma unroll
        for (int l = 0; l < 2; l++) async_ld16(g + aoff[l], d + adst[l]);
    };
    auto stageB = [&](int kt, int kh, int p) {
        const short* g = Bb + kt * 64 + kh * 32;
        char* d = lds + p * BUFB + 2 * AHB + kh * BHB;
#pragma unroll
        for (int l = 0; l < LB; l++) async_ld16(g + boff[l], d + bdst[l]);
    };

    f32x4 acc[8][NF] = {};
    bf16x8 afE[4], bfE[NF], afO[4], bfO[NF], afS[4];

    // ---- prologue: 3 half-pair groups in flight, prefetch E from (0,kh0) ----
    stageA(0, 0, 0); stageB(0, 0, 0);      // group 1: (0,kh0)
    stageA(0, 1, 0); stageB(0, 1, 0);      // group 2: (0,kh1)
    {
        int k1 = (NT > 1) ? 1 : 0;
        stageA(k1, 0, 1); stageB(k1, 0, 1); // group 3: (1,kh0)
    }
    asm volatile("s_waitcnt vmcnt(%0)" :: "n"(2 * (2 + LB)) : "memory"); // grp1 done
    asm volatile("s_barrier" ::: "memory");
    LDB_P(E, lds, 0); LDA03_P(E, lds, 0);  // fragments for phase A(0)
    asm volatile("s_waitcnt vmcnt(%0)" :: "n"(2 + LB) : "memory");        // grp2 done
    asm volatile("s_barrier" ::: "memory");

    // ---- main loop: 2 phases per K-tile, fragments prefetched 1 phase ahead ----
    for (int kt = 0; kt < NT; kt++) {
        const int p = kt & 1;
        const char* base = lds + p * BUFB;
        const char* baseN = lds + (p ^ 1) * BUFB;
        const int k1 = (kt + 1 < NT) ? (kt + 1) : (NT - 1);
        const int k2 = (kt + 2 < NT) ? (kt + 2) : (NT - 1);

        // phase A: MFMA on E (buf[p].kh0); in-phase afS; prefetch O <- buf[p].kh1
        LDA47_S(base, 0);
        LDB_P(O, base, 1); LDA03_P(O, base, 1);
        stageA(k1, 1, p ^ 1); stageB(k1, 1, p ^ 1);
        __builtin_amdgcn_sched_barrier(0);
        __builtin_amdgcn_s_setprio(1);
        MFMA_PH(E);
        PHASE_TAIL();

        // phase B: MFMA on O (buf[p].kh1); in-phase afS; prefetch E <- buf[p^1].kh0
        LDA47_S(base, 1);
        LDB_P(E, baseN, 0); LDA03_P(E, baseN, 0);
        stageA(k2, 0, p); stageB(k2, 0, p);
        __builtin_amdgcn_sched_barrier(0);
        __builtin_amdgcn_s_setprio(1);
        MFMA_PH(O);
        PHASE_TAIL();
    }
    // drain stray clamped stages before LDS reuse / wave exit
    asm volatile("s_waitcnt vmcnt(0)" ::: "memory");

    // ---- epilogue: C/D layout col = lane&15, row = (lane>>4)*4 + reg ----
    const int crow = (lane >> 4) * 4, ccol = lane & 15;
    if (EPI == 0) {
        // LDS-staged coalesced f32 stores, 2 passes of 64 M-rows per half.
        float* lf = (float*)lds;
#pragma unroll
        for (int p2 = 0; p2 < 2; p2++) {
            __syncthreads();   // pass p2 reuses LDS; prior reads complete
#pragma unroll
            for (int i = 0; i < 4; i++) {
                const int ii = p2 * 4 + i;
#pragma unroll
                for (int j = 0; j < NF; j++)
#pragma unroll
                    for (int r = 0; r < 4; r++) {
                        int rl = wm + ii * 16 + crow + r;            // [0,256)
                        int slot = (rl & 63) | ((rl >> 7) << 6);     // [0,128)
                        lf[slot * 260 + wn + j * 16 + ccol] = acc[ii][j][r];
                    }
            }
            __syncthreads();
#pragma unroll
            for (int rep = 0; rep < 16; rep++) {
                int idx = rep * 512 + t;          // 128 slots x 64 col4s
                int slot = idx >> 6, c4 = idx & 63;
                int rl = (slot & 63) + p2 * 64 + ((slot >> 6) << 7);
                float4 v = *(const float4*)&lf[slot * 260 + c4 * 4];
                *(float4*)(Cf + (size_t)(bm + rl) * N + bn + c4 * 4) = v;
            }
        }
    } else {
#pragma unroll
        for (int i = 0; i < 8; i++)
#pragma unroll
            for (int j = 0; j < NF; j++) {
                const int col = bn + wn + j * 16 + ccol;
                const int rowb = bm + wm + i * 16 + crow;
                // cols [0,2048) are q|k: RoPE. 16-col tile never straddles the
                // 2048 boundary or a 128 head boundary -> wave-uniform branch.
                const bool qk = col < 2048;
                const int fi = (col & 127) >> 1;
                const bool even = (col & 1) == 0;
                uint32_t* Cd = (uint32_t*)(Cb + ((size_t)rowb * N + (col & ~1)));
#pragma unroll
                for (int r = 0; r < 4; r++) {
                    float v = acc[i][j][r];
                    if (qk) {
                        int s = (rowb + r) & (S_ - 1);
                        float2 cs = ctab[s * 64 + fi];
                        float pp = __shfl_xor(v, 1);
                        v = even ? v * cs.x - pp * cs.y : v * cs.x + pp * cs.y;
                    }
                    int hb = (int)(unsigned short)f2bf(v);
                    int pb = __shfl_xor(hb, 1);
                    if (even)
                        Cd[(size_t)r * (N >> 1)] = (uint32_t)(hb | (pb << 16));
                }
            }
    }
}

// ---------------- sliding-window attn + gate + silu(z) + RMSNorm -> yn bf16 ----------------
__global__ __launch_bounds__(256) void k_attn(const unsigned short* __restrict__ qkvz,
                                              const float* __restrict__ bgag,
                                              const float* __restrict__ norm_w,
                                              short* __restrict__ yn) {
    const int m = blockIdx.x;
    const int s = m & (S_ - 1);
    const int t = threadIdx.x;
    __shared__ unsigned short kvls[5][2048];  // rows m-off, cols [1024,3072) = k|v
    __shared__ unsigned short qzls[2048];     // [0,1024)=q row m, [1024,2048)=z row m
    __shared__ float sc[NH_][5];
    __shared__ float red[4];
    const int nOff = (s < 4 ? s : 4) + 1;

    for (int off = 0; off < 5; off++) {
        if (off < nOff) {
            const ushort4* r = (const ushort4*)(qkvz + (size_t)(m - off) * NQKVZ + 1024);
            ushort4* d = (ushort4*)kvls[off];
            d[t] = r[t];
            d[t + 256] = r[t + 256];
        }
    }
    {
        const unsigned short* r = qkvz + (size_t)m * NQKVZ;
        ushort4* d = (ushort4*)qzls;
        d[t] = ((const ushort4*)r)[t];                    // q
        d[256 + t] = ((const ushort4*)(r + 3072))[t];     // z
    }
    __syncthreads();

    // scores: 8 heads x 32 lanes each; each lane covers 4 d's
    {
        const int h = t >> 5, l = t & 31;
        float qv[4];
#pragma unroll
        for (int d = 0; d < 4; d++) qv[d] = bf2f(qzls[h * 128 + l * 4 + d]);
        const float ag = bgag[(size_t)m * 16 + 8 + h];
#pragma unroll
        for (int off = 0; off < 5; off++) {
            float acc = 0.f;
            if (off < nOff) {
#pragma unroll
                for (int d = 0; d < 4; d++)
                    acc += qv[d] * bf2f(kvls[off][h * 128 + l * 4 + d]);
            }
#pragma unroll
            for (int w = 1; w < 32; w <<= 1) acc += __shfl_xor(acc, w);
            if (l == 0) {
                float val = 0.f;
                if (off < nOff) {
                    float bg = bgag[(size_t)(m - off) * 16 + h];
                    float g = 1.f / (1.f + expf(-ag * bg));
                    val = acc * 0.08838834764831845f * g;   // 1/sqrt(128) * gate
                }
                sc[h][off] = val;
            }
        }
    }
    __syncthreads();

    // phase 2: 4 consecutive elements per thread
    const int e0 = t * 4, h = e0 >> 7;
    float o[4] = {0.f, 0.f, 0.f, 0.f};
    if (s == 0) {
#pragma unroll
        for (int d = 0; d < 4; d++) o[d] = bf2f(kvls[0][1024 + e0 + d]);
    } else {
        for (int off = 0; off < nOff; off++) {
            float w = sc[h][off];
#pragma unroll
            for (int d = 0; d < 4; d++) o[d] += w * bf2f(kvls[off][1024 + e0 + d]);
        }
    }
    float y[4], zs4[4], ss = 0.f;
#pragma unroll
    for (int d = 0; d < 4; d++) {
        float z = bf2f(qzls[1024 + e0 + d]);
        float sg = 1.f / (1.f + expf(-z));
        y[d] = o[d] * sg;
        zs4[d] = z * sg;
        ss += y[d] * y[d];
    }
    const int wave = t >> 6, lane = t & 63;
#pragma unroll
    for (int w = 1; w < 64; w <<= 1) ss += __shfl_xor(ss, w);
    if (lane == 0) red[wave] = ss;
    __syncthreads();
    float tot = red[0] + red[1] + red[2] + red[3];
    float rinv = 1.f / sqrtf(tot * (1.0f / 1024.0f) + 1e-6f);
    short4 ov;
    ov.x = f2bf(y[0] * rinv * norm_w[e0 + 0] * zs4[0]);
    ov.y = f2bf(y[1] * rinv * norm_w[e0 + 1] * zs4[1]);
    ov.z = f2bf(y[2] * rinv * norm_w[e0 + 2] * zs4[2]);
    ov.w = f2bf(y[3] * rinv * norm_w[e0 + 3] * zs4[3]);
    ((short4*)yn)[(size_t)m * 256 + t] = ov;
}

extern "C" void kernel_launch(void* const* d_in, const int* in_sizes, int n_in,
                              void* d_out, int out_size, void* d_ws, size_t ws_size,
                              hipStream_t stream) {
    const float* x      = (const float*)d_in[0];
    const float* W_qkv  = (const float*)d_in[1];
    const float* W_z    = (const float*)d_in[2];
    const float* W_b    = (const float*)d_in[3];
    const float* W_a    = (const float*)d_in[4];
    const float* norm_w = (const float*)d_in[5];
    const float* W_out  = (const float*)d_in[6];
    float* out = (float*)d_out;

    // workspace (~135 MB)
    char* ws = (char*)d_ws;
    short* xb    = (short*)ws;          ws += (size_t)MR * H_ * 2;       // 32 MB
    short* Wt1   = (short*)ws;          ws += (size_t)NQKVZ * H_ * 2;    // 16 MB
    short* Wt2   = (short*)ws;          ws += (size_t)H_ * KD_ * 2;      //  4 MB
    unsigned short* qkvzb = (unsigned short*)ws; ws += (size_t)MR * NQKVZ * 2; // 64 MB
    float* bgag  = (float*)ws;          ws += (size_t)MR * 16 * 4;       // 0.5 MB
    short* yn    = (short*)ws;          ws += (size_t)MR * KD_ * 2;      // 16 MB
    float2* ctab = (float2*)ws;         ws += (size_t)S_ * 64 * 8;       //  2 MB
    float* Wba   = (float*)ws;          ws += (size_t)16 * 2048 * 4;     // 128 KB

    // 0. transpose W_b|W_a for contiguous reads
    k_wba<<<16 * 2048 / 256, 256, 0, stream>>>(W_b, W_a, Wba);
    // 1. fused convert x->bf16 + bg/ag skinny GEMM (4 rows/block, 4x W reuse)
    k_cvt_bgag4<<<MR / 4, 256, 0, stream>>>(x, xb, Wba, bgag);
    // 2. transpose-convert weights
    k_transpose_cvt<<<dim3(3072 / 32, 2048 / 32), dim3(32, 8), 0, stream>>>(W_qkv, Wt1, 2048, 3072);
    k_transpose_cvt<<<dim3(1024 / 32, 2048 / 32), dim3(32, 8), 0, stream>>>(W_z, Wt1 + (size_t)3072 * 2048, 2048, 1024);
    k_transpose_cvt<<<dim3(2048 / 32, 1024 / 32), dim3(32, 8), 0, stream>>>(W_out, Wt2, 1024, 2048);
    // 3. rope table
    k_ropetab<<<S_ * 64 / 256, 256, 0, stream>>>(ctab);
    // 4. GEMM1 (frag-prefetch 256², fused rope epilogue): qkvz = rope(x @ [W_qkv|W_z])
    k_gemm256<256, 1><<<(MR / 256) * (NQKVZ / 256), 512, 0, stream>>>(
        xb, Wt1, nullptr, qkvzb, ctab, MR, NQKVZ, H_);
    // 5. attention window + gating + RMSNorm -> yn (bf16)
    k_attn<<<MR, 256, 0, stream>>>(qkvzb, bgag, norm_w, yn);
    // 6. GEMM2 (frag-prefetch 256x256, coalesced LDS-staged epilogue): out = yn @ W_out
    k_gemm256<256, 0><<<(MR / 256) * (H_ / 256), 512, 0, stream>>>(
        yn, Wt2, out, nullptr, nullptr, MR, H_, KD_);
}

// Round 7
// 440.067 us; speedup vs baseline: 1.0765x; 1.0246x over previous
//
#include <hip/hip_runtime.h>
#include <hip/hip_bf16.h>
#include <stdint.h>

#define B_   2
#define S_   4096
#define H_   2048
#define NH_  8
#define D_   128
#define KD_  1024
#define MR   (B_ * S_)          // 8192 rows
#define NQKVZ 4096              // q|k|v|z concatenated width

typedef __attribute__((ext_vector_type(8))) short bf16x8;
typedef __attribute__((ext_vector_type(4))) float f32x4;

__device__ __forceinline__ short f2bf(float f) {
    union { float f; uint32_t u; } v; v.f = f;
    uint32_t r = v.u + 0x7FFF + ((v.u >> 16) & 1);   // RNE
    return (short)(r >> 16);
}
__device__ __forceinline__ float bf2f(unsigned short u) {
    union { uint32_t u; float f; } v; v.u = (uint32_t)u << 16; return v.f;
}

__device__ __forceinline__ void async_ld16(const void* g, void* l) {
    __builtin_amdgcn_global_load_lds(
        (const __attribute__((address_space(1))) uint32_t*)g,
        (__attribute__((address_space(3))) uint32_t*)l, 16, 0, 0);
}

// ---------------- W_b|W_a -> transposed [16][2048] f32 (contiguous per col) ----------------
__global__ __launch_bounds__(256) void k_wba(const float* __restrict__ Wb,
                                             const float* __restrict__ Wa,
                                             float* __restrict__ Wba) {
    int idx = blockIdx.x * 256 + threadIdx.x;      // 16 * 2048
    int k = idx & 2047, c = idx >> 11;
    float v = (c < 8) ? Wb[(size_t)k * 8 + c] : Wa[(size_t)k * 8 + (c - 8)];
    Wba[(size_t)c * 2048 + k] = v;
}

// ---------------- fused: 4 x rows -> bf16 + bgag skinny GEMM (4x W reuse) ----------------
__global__ __launch_bounds__(256) void k_cvt_bgag4(const float* __restrict__ x,
                                                   short* __restrict__ xb,
                                                   const float* __restrict__ Wba,
                                                   float* __restrict__ bgag) {
    const int m0 = blockIdx.x * 4, t = threadIdx.x;
    __shared__ float xs[4][2048];
    __shared__ float part[4][256];
#pragma unroll
    for (int rr = 0; rr < 4; rr++) {
        const float4* xr = (const float4*)(x + (size_t)(m0 + rr) * H_);
        float4 a = xr[t], b = xr[t + 256];
        ((float4*)xs[rr])[t] = a;
        ((float4*)xs[rr])[t + 256] = b;
        short4 oa, ob;
        oa.x = f2bf(a.x); oa.y = f2bf(a.y); oa.z = f2bf(a.z); oa.w = f2bf(a.w);
        ob.x = f2bf(b.x); ob.y = f2bf(b.y); ob.z = f2bf(b.z); ob.w = f2bf(b.w);
        short4* xo = (short4*)(xb + (size_t)(m0 + rr) * H_);
        xo[t] = oa;
        xo[t + 256] = ob;
    }
    __syncthreads();
    const int c = t & 15, seg = t >> 4;            // 16 cols x 16 k-segments
    const int kb = seg * 128;
    const float4* W4 = (const float4*)(Wba + (size_t)c * 2048 + kb);
    const float4* x0 = (const float4*)&xs[0][kb];
    const float4* x1 = (const float4*)&xs[1][kb];
    const float4* x2 = (const float4*)&xs[2][kb];
    const float4* x3 = (const float4*)&xs[3][kb];
    float a0 = 0.f, a1 = 0.f, a2 = 0.f, a3 = 0.f;
#pragma unroll 8
    for (int k4 = 0; k4 < 32; k4++) {
        float4 w = W4[k4];
        float4 v0 = x0[k4], v1 = x1[k4], v2 = x2[k4], v3 = x3[k4];
        a0 += w.x * v0.x + w.y * v0.y + w.z * v0.z + w.w * v0.w;
        a1 += w.x * v1.x + w.y * v1.y + w.z * v1.z + w.w * v1.w;
        a2 += w.x * v2.x + w.y * v2.y + w.z * v2.z + w.w * v2.w;
        a3 += w.x * v3.x + w.y * v3.y + w.z * v3.z + w.w * v3.w;
    }
    part[0][t] = a0; part[1][t] = a1; part[2][t] = a2; part[3][t] = a3;
    __syncthreads();
    if (t < 64) {
        int rr = t >> 4, cc = t & 15;
        float s = 0.f;
#pragma unroll
        for (int j = 0; j < 16; j++) s += part[rr][j * 16 + cc];
        bgag[(size_t)(m0 + rr) * 16 + cc] = s;   // [0..8)=bg, [8..16)=ag
    }
}

// ---------------- transpose + convert: W (KxN f32) -> Wt (NxK bf16) ----------------
__global__ __launch_bounds__(256) void k_transpose_cvt(const float* __restrict__ W,
                                                       short* __restrict__ Wt,
                                                       int K, int N) {
    __shared__ float tile[32][33];
    int n0 = blockIdx.x * 32, k0 = blockIdx.y * 32;
    int tx = threadIdx.x, ty = threadIdx.y;   // 32 x 8
#pragma unroll
    for (int i = 0; i < 32; i += 8)
        tile[ty + i][tx] = W[(size_t)(k0 + ty + i) * N + n0 + tx];
    __syncthreads();
#pragma unroll
    for (int i = 0; i < 32; i += 8)
        Wt[(size_t)(n0 + ty + i) * K + k0 + tx] = f2bf(tile[tx][ty + i]);
}

// ---------------- RoPE table: ctab[s][i] = {cos(s*inv_i), sin(s*inv_i)} ----------------
__global__ __launch_bounds__(256) void k_ropetab(float2* __restrict__ ctab) {
    int idx = blockIdx.x * 256 + threadIdx.x;   // S_*64
    int i = idx & 63, s = idx >> 6;
    float inv = exp2f(-(float)i * (2.0f / 128.0f) * 19.931568569324174f);
    float f = (float)s * inv;
    float sn, cs;
    sincosf(f, &sn, &cs);
    ctab[idx] = make_float2(cs, sn);
}

// ====== 256x256 MFMA GEMM — R5 K-loop + R6 coalesced EPI=0 epilogue (UNCHANGED) ======
#define PHASE_TAIL() \
    __builtin_amdgcn_s_setprio(0); \
    asm volatile("s_waitcnt vmcnt(%0)" :: "n"(2 + LB) : "memory"); \
    asm volatile("s_barrier" ::: "memory")
#define LDB_P(SET, BASE, KH) \
    _Pragma("unroll") for (int j = 0; j < NF; j++) \
        bf##SET[j] = *(const bf16x8*)((BASE) + 2 * AHB + (KH) * BHB + (wn + j * 16 + mrow) * 64 + kcA)
#define LDA03_P(SET, BASE, KH) \
    _Pragma("unroll") for (int i = 0; i < 4; i++) \
        af##SET[i] = *(const bf16x8*)((BASE) + (KH) * AHB + (wm + i * 16 + mrow) * 64 + kcA)
#define LDA47_S(BASE, KH) \
    _Pragma("unroll") for (int i = 0; i < 4; i++) \
        afS[i] = *(const bf16x8*)((BASE) + (KH) * AHB + (wm + 64 + i * 16 + mrow) * 64 + kcA)
#define MFMA_PH(SET) \
    _Pragma("unroll") for (int i = 0; i < 4; i++) \
    _Pragma("unroll") for (int j = 0; j < NF; j++) \
        acc[i][j] = __builtin_amdgcn_mfma_f32_16x16x32_bf16(af##SET[i], bf##SET[j], acc[i][j], 0, 0, 0); \
    _Pragma("unroll") for (int i = 0; i < 4; i++) \
    _Pragma("unroll") for (int j = 0; j < NF; j++) \
        acc[4 + i][j] = __builtin_amdgcn_mfma_f32_16x16x32_bf16(afS[i], bf##SET[j], acc[4 + i][j], 0, 0, 0)

template <int BN, int EPI>
__global__ __launch_bounds__(512, 2) void k_gemm256(const short* __restrict__ A,
                                                    const short* __restrict__ Bt,
                                                    float* __restrict__ Cf,
                                                    unsigned short* __restrict__ Cb,
                                                    const float2* __restrict__ ctab,
                                                    int M, int N, int K) {
    constexpr int BM = 256;
    constexpr int NF = BN / 64;
    constexpr int LB = BN / 128;
    constexpr int AHB = BM * 64;
    constexpr int BHB = BN * 64;
    constexpr int BUFB = 2 * AHB + 2 * BHB;
    constexpr int LDSB = (EPI == 0) ? 133120 : 2 * BUFB;
    __shared__ __align__(16) char lds[LDSB];

    const int t = threadIdx.x;
    const int lane = t & 63, wave = t >> 6;
    const int mrow = lane & 15;
    const int kcA = (((lane >> 4) ^ ((mrow >> 1) & 3)) * 16);

    const int nwg = gridDim.x;
    const int w0 = blockIdx.x;
    const int wg = (w0 & 7) * (nwg >> 3) + (w0 >> 3);
    const int NB = N / BN;
    const int bn = (wg % NB) * BN;
    const int bm = (wg / NB) * BM;

    const int wm = (wave >> 2) * 128;
    const int wn = (wave & 3) * (BN / 4);

    const short* __restrict__ Ab = A + (size_t)bm * K;
    const short* __restrict__ Bb = Bt + (size_t)bn * K;

    int aoff[2], adst[2];
#pragma unroll
    for (int l = 0; l < 2; l++) {
        int c = t + l * 512;
        int row = c >> 2;
        int kcg = (c & 3) ^ ((row >> 1) & 3);
        aoff[l] = row * K + kcg * 8;
        adst[l] = c * 16;
    }
    int boff[LB], bdst[LB];
#pragma unroll
    for (int l = 0; l < LB; l++) {
        int c = t + l * 512;
        int row = c >> 2;
        int kcg = (c & 3) ^ ((row >> 1) & 3);
        boff[l] = row * K + kcg * 8;
        bdst[l] = c * 16;
    }

    const int NT = K >> 6;

    auto stageA = [&](int kt, int kh, int p) {
        const short* g = Ab + kt * 64 + kh * 32;
        char* d = lds + p * BUFB + kh * AHB;
#pragma unroll
        for (int l = 0; l < 2; l++) async_ld16(g + aoff[l], d + adst[l]);
    };
    auto stageB = [&](int kt, int kh, int p) {
        const short* g = Bb + kt * 64 + kh * 32;
        char* d = lds + p * BUFB + 2 * AHB + kh * BHB;
#pragma unroll
        for (int l = 0; l < LB; l++) async_ld16(g + boff[l], d + bdst[l]);
    };

    f32x4 acc[8][NF] = {};
    bf16x8 afE[4], bfE[NF], afO[4], bfO[NF], afS[4];

    stageA(0, 0, 0); stageB(0, 0, 0);
    stageA(0, 1, 0); stageB(0, 1, 0);
    {
        int k1 = (NT > 1) ? 1 : 0;
        stageA(k1, 0, 1); stageB(k1, 0, 1);
    }
    asm volatile("s_waitcnt vmcnt(%0)" :: "n"(2 * (2 + LB)) : "memory");
    asm volatile("s_barrier" ::: "memory");
    LDB_P(E, lds, 0); LDA03_P(E, lds, 0);
    asm volatile("s_waitcnt vmcnt(%0)" :: "n"(2 + LB) : "memory");
    asm volatile("s_barrier" ::: "memory");

    for (int kt = 0; kt < NT; kt++) {
        const int p = kt & 1;
        const char* base = lds + p * BUFB;
        const char* baseN = lds + (p ^ 1) * BUFB;
        const int k1 = (kt + 1 < NT) ? (kt + 1) : (NT - 1);
        const int k2 = (kt + 2 < NT) ? (kt + 2) : (NT - 1);

        LDA47_S(base, 0);
        LDB_P(O, base, 1); LDA03_P(O, base, 1);
        stageA(k1, 1, p ^ 1); stageB(k1, 1, p ^ 1);
        __builtin_amdgcn_sched_barrier(0);
        __builtin_amdgcn_s_setprio(1);
        MFMA_PH(E);
        PHASE_TAIL();

        LDA47_S(base, 1);
        LDB_P(E, baseN, 0); LDA03_P(E, baseN, 0);
        stageA(k2, 0, p); stageB(k2, 0, p);
        __builtin_amdgcn_sched_barrier(0);
        __builtin_amdgcn_s_setprio(1);
        MFMA_PH(O);
        PHASE_TAIL();
    }
    asm volatile("s_waitcnt vmcnt(0)" ::: "memory");

    const int crow = (lane >> 4) * 4, ccol = lane & 15;
    if (EPI == 0) {
        float* lf = (float*)lds;
#pragma unroll
        for (int p2 = 0; p2 < 2; p2++) {
            __syncthreads();
#pragma unroll
            for (int i = 0; i < 4; i++) {
                const int ii = p2 * 4 + i;
#pragma unroll
                for (int j = 0; j < NF; j++)
#pragma unroll
                    for (int r = 0; r < 4; r++) {
                        int rl = wm + ii * 16 + crow + r;
                        int slot = (rl & 63) | ((rl >> 7) << 6);
                        lf[slot * 260 + wn + j * 16 + ccol] = acc[ii][j][r];
                    }
            }
            __syncthreads();
#pragma unroll
            for (int rep = 0; rep < 16; rep++) {
                int idx = rep * 512 + t;
                int slot = idx >> 6, c4 = idx & 63;
                int rl = (slot & 63) + p2 * 64 + ((slot >> 6) << 7);
                float4 v = *(const float4*)&lf[slot * 260 + c4 * 4];
                *(float4*)(Cf + (size_t)(bm + rl) * N + bn + c4 * 4) = v;
            }
        }
    } else {
#pragma unroll
        for (int i = 0; i < 8; i++)
#pragma unroll
            for (int j = 0; j < NF; j++) {
                const int col = bn + wn + j * 16 + ccol;
                const int rowb = bm + wm + i * 16 + crow;
                const bool qk = col < 2048;
                const int fi = (col & 127) >> 1;
                const bool even = (col & 1) == 0;
                uint32_t* Cd = (uint32_t*)(Cb + ((size_t)rowb * N + (col & ~1)));
#pragma unroll
                for (int r = 0; r < 4; r++) {
                    float v = acc[i][j][r];
                    if (qk) {
                        int s = (rowb + r) & (S_ - 1);
                        float2 cs = ctab[s * 64 + fi];
                        float pp = __shfl_xor(v, 1);
                        v = even ? v * cs.x - pp * cs.y : v * cs.x + pp * cs.y;
                    }
                    int hb = (int)(unsigned short)f2bf(v);
                    int pb = __shfl_xor(hb, 1);
                    if (even)
                        Cd[(size_t)r * (N >> 1)] = (uint32_t)(hb | (pb << 16));
                }
            }
    }
}

// ====== R7: sliding-window attn, 4 rows/block (2x KV traffic cut, no q/z LDS trip) ======
// rows m0..m0+3 (same sequence: S%4==0). kvls ring holds global rows m0-4..m0+3.
// Boundary: only first block of a sequence has short windows; row r uses ring
// idx r+4-off with off<=min(s_r,4) => idx>=4 there, so clamped rows 0..3 are
// provably never consumed.
__global__ __launch_bounds__(256) void k_attn4(const unsigned short* __restrict__ qkvz,
                                               const float* __restrict__ bgag,
                                               const float* __restrict__ norm_w,
                                               short* __restrict__ yn) {
    const int m0 = blockIdx.x * 4;
    const int s0 = m0 & (S_ - 1);
    const int t = threadIdx.x;
    __shared__ unsigned short kvls[8][2048];   // cols [1024,3072) = k|v
    __shared__ float sc[4][NH_][5];
    __shared__ float red[4][4];                // [wave][row]

    // stage 8 kv rows: one uint4 (16B) per thread per row, coalesced
#pragma unroll
    for (int i = 0; i < 8; i++) {
        int g = m0 - 4 + i;
        g = (g < 0) ? 0 : g;                   // only block 0; values unused
        const uint4* src = (const uint4*)(qkvz + (size_t)g * NQKVZ + 1024);
        ((uint4*)kvls[i])[t] = src[t];
    }
    __syncthreads();

    // scores: t -> (row, head, lane8) = 4 x 8 x 8; q read direct from global
    {
        const int r = t >> 6, h = (t >> 3) & 7, l8 = t & 7;
        const int sr = s0 + r;
        const int nOff = (sr < 4 ? sr : 4) + 1;
        float qv[16];
        {
            const unsigned short* qg = qkvz + (size_t)(m0 + r) * NQKVZ + h * 128 + l8 * 16;
#pragma unroll
            for (int d = 0; d < 16; d++) qv[d] = bf2f(qg[d]);
        }
        const float ag = bgag[(size_t)(m0 + r) * 16 + 8 + h];
#pragma unroll
        for (int off = 0; off < 5; off++) {
            float acc = 0.f;
            const unsigned short* kk = kvls[r + 4 - off] + h * 128 + l8 * 16;
#pragma unroll
            for (int d = 0; d < 16; d++) acc += qv[d] * bf2f(kk[d]);
#pragma unroll
            for (int w = 1; w < 8; w <<= 1) acc += __shfl_xor(acc, w);
            if (l8 == 0) {
                float val = 0.f;
                if (off < nOff) {
                    float bg = bgag[(size_t)(m0 + r - off) * 16 + h];
                    float g = 1.f / (1.f + expf(-ag * bg));
                    val = acc * 0.08838834764831845f * g;   // 1/sqrt(128) * gate
                }
                sc[r][h][off] = val;
            }
        }
    }
    __syncthreads();

    // phase 2: thread t covers elements e0..e0+3 of each of the 4 rows
    const int e0 = t * 4, h2 = t >> 5;
    float yv[4][4], zs[4][4], ssr[4];
    float nw[4];
    {
        const float4 n4 = *(const float4*)(norm_w + e0);
        nw[0] = n4.x; nw[1] = n4.y; nw[2] = n4.z; nw[3] = n4.w;
    }
#pragma unroll
    for (int r = 0; r < 4; r++) {
        const int sr = s0 + r;
        float o[4] = {0.f, 0.f, 0.f, 0.f};
        if (sr == 0) {
#pragma unroll
            for (int d = 0; d < 4; d++) o[d] = bf2f(kvls[r + 4][1024 + e0 + d]);
        } else {
            const int nOff = (sr < 4 ? sr : 4) + 1;
            for (int off = 0; off < nOff; off++) {
                float w = sc[r][h2][off];
#pragma unroll
                for (int d = 0; d < 4; d++)
                    o[d] += w * bf2f(kvls[r + 4 - off][1024 + e0 + d]);
            }
        }
        // z read direct from global (single use), 8B coalesced
        const unsigned short* zg = qkvz + (size_t)(m0 + r) * NQKVZ + 3072 + e0;
        float ss = 0.f;
#pragma unroll
        for (int d = 0; d < 4; d++) {
            float z = bf2f(zg[d]);
            float sg = 1.f / (1.f + expf(-z));
            yv[r][d] = o[d] * sg;
            zs[r][d] = z * sg;
            ss += yv[r][d] * yv[r][d];
        }
        ssr[r] = ss;
    }
    const int wave = t >> 6, lane = t & 63;
#pragma unroll
    for (int r = 0; r < 4; r++)
#pragma unroll
        for (int w = 1; w < 64; w <<= 1) ssr[r] += __shfl_xor(ssr[r], w);
    if (lane == 0) {
        red[wave][0] = ssr[0]; red[wave][1] = ssr[1];
        red[wave][2] = ssr[2]; red[wave][3] = ssr[3];
    }
    __syncthreads();
#pragma unroll
    for (int r = 0; r < 4; r++) {
        float tot = red[0][r] + red[1][r] + red[2][r] + red[3][r];
        float rinv = 1.f / sqrtf(tot * (1.0f / 1024.0f) + 1e-6f);
        short4 ov;
        ov.x = f2bf(yv[r][0] * rinv * nw[0] * zs[r][0]);
        ov.y = f2bf(yv[r][1] * rinv * nw[1] * zs[r][1]);
        ov.z = f2bf(yv[r][2] * rinv * nw[2] * zs[r][2]);
        ov.w = f2bf(yv[r][3] * rinv * nw[3] * zs[r][3]);
        ((short4*)yn)[(size_t)(m0 + r) * 256 + t] = ov;
    }
}

extern "C" void kernel_launch(void* const* d_in, const int* in_sizes, int n_in,
                              void* d_out, int out_size, void* d_ws, size_t ws_size,
                              hipStream_t stream) {
    const float* x      = (const float*)d_in[0];
    const float* W_qkv  = (const float*)d_in[1];
    const float* W_z    = (const float*)d_in[2];
    const float* W_b    = (const float*)d_in[3];
    const float* W_a    = (const float*)d_in[4];
    const float* norm_w = (const float*)d_in[5];
    const float* W_out  = (const float*)d_in[6];
    float* out = (float*)d_out;

    // workspace (~135 MB)
    char* ws = (char*)d_ws;
    short* xb    = (short*)ws;          ws += (size_t)MR * H_ * 2;       // 32 MB
    short* Wt1   = (short*)ws;          ws += (size_t)NQKVZ * H_ * 2;    // 16 MB
    short* Wt2   = (short*)ws;          ws += (size_t)H_ * KD_ * 2;      //  4 MB
    unsigned short* qkvzb = (unsigned short*)ws; ws += (size_t)MR * NQKVZ * 2; // 64 MB
    float* bgag  = (float*)ws;          ws += (size_t)MR * 16 * 4;       // 0.5 MB
    short* yn    = (short*)ws;          ws += (size_t)MR * KD_ * 2;      // 16 MB
    float2* ctab = (float2*)ws;         ws += (size_t)S_ * 64 * 8;       //  2 MB
    float* Wba   = (float*)ws;          ws += (size_t)16 * 2048 * 4;     // 128 KB

    // 0. transpose W_b|W_a for contiguous reads
    k_wba<<<16 * 2048 / 256, 256, 0, stream>>>(W_b, W_a, Wba);
    // 1. fused convert x->bf16 + bg/ag skinny GEMM (4 rows/block, 4x W reuse)
    k_cvt_bgag4<<<MR / 4, 256, 0, stream>>>(x, xb, Wba, bgag);
    // 2. transpose-convert weights
    k_transpose_cvt<<<dim3(3072 / 32, 2048 / 32), dim3(32, 8), 0, stream>>>(W_qkv, Wt1, 2048, 3072);
    k_transpose_cvt<<<dim3(1024 / 32, 2048 / 32), dim3(32, 8), 0, stream>>>(W_z, Wt1 + (size_t)3072 * 2048, 2048, 1024);
    k_transpose_cvt<<<dim3(2048 / 32, 1024 / 32), dim3(32, 8), 0, stream>>>(W_out, Wt2, 1024, 2048);
    // 3. rope table
    k_ropetab<<<S_ * 64 / 256, 256, 0, stream>>>(ctab);
    // 4. GEMM1 (frag-prefetch 256², fused rope epilogue): qkvz = rope(x @ [W_qkv|W_z])
    k_gemm256<256, 1><<<(MR / 256) * (NQKVZ / 256), 512, 0, stream>>>(
        xb, Wt1, nullptr, qkvzb, ctab, MR, NQKVZ, H_);
    // 5. attention window + gating + RMSNorm -> yn (bf16), 4 rows/block
    k_attn4<<<MR / 4, 256, 0, stream>>>(qkvzb, bgag, norm_w, yn);
    // 6. GEMM2 (frag-prefetch 256x256, coalesced LDS-staged epilogue): out = yn @ W_out
    k_gemm256<256, 0><<<(MR / 256) * (H_ / 256), 512, 0, stream>>>(
        yn, Wt2, out, nullptr, nullptr, MR, H_, KD_);
}

// Round 8
// 436.724 us; speedup vs baseline: 1.0848x; 1.0077x over previous
//
#include <hip/hip_runtime.h>
#include <hip/hip_bf16.h>
#include <stdint.h>

#define B_   2
#define S_   4096
#define H_   2048
#define NH_  8
#define D_   128
#define KD_  1024
#define MR   (B_ * S_)          // 8192 rows
#define NQKVZ 4096              // q|k|v|z concatenated width

typedef __attribute__((ext_vector_type(8))) short bf16x8;
typedef __attribute__((ext_vector_type(4))) float f32x4;

__device__ __forceinline__ short f2bf(float f) {
    union { float f; uint32_t u; } v; v.f = f;
    uint32_t r = v.u + 0x7FFF + ((v.u >> 16) & 1);   // RNE
    return (short)(r >> 16);
}
__device__ __forceinline__ float bf2f(unsigned short u) {
    union { uint32_t u; float f; } v; v.u = (uint32_t)u << 16; return v.f;
}

__device__ __forceinline__ void async_ld16(const void* g, void* l) {
    __builtin_amdgcn_global_load_lds(
        (const __attribute__((address_space(1))) uint32_t*)g,
        (__attribute__((address_space(3))) uint32_t*)l, 16, 0, 0);
}

// ---------------- W_b|W_a -> transposed [16][2048] f32 (contiguous per col) ----------------
__global__ __launch_bounds__(256) void k_wba(const float* __restrict__ Wb,
                                             const float* __restrict__ Wa,
                                             float* __restrict__ Wba) {
    int idx = blockIdx.x * 256 + threadIdx.x;      // 16 * 2048
    int k = idx & 2047, c = idx >> 11;
    float v = (c < 8) ? Wb[(size_t)k * 8 + c] : Wa[(size_t)k * 8 + (c - 8)];
    Wba[(size_t)c * 2048 + k] = v;
}

// ---------------- fused: 4 x rows -> bf16 + bgag skinny GEMM (4x W reuse) ----------------
__global__ __launch_bounds__(256) void k_cvt_bgag4(const float* __restrict__ x,
                                                   short* __restrict__ xb,
                                                   const float* __restrict__ Wba,
                                                   float* __restrict__ bgag) {
    const int m0 = blockIdx.x * 4, t = threadIdx.x;
    __shared__ float xs[4][2048];
    __shared__ float part[4][256];
#pragma unroll
    for (int rr = 0; rr < 4; rr++) {
        const float4* xr = (const float4*)(x + (size_t)(m0 + rr) * H_);
        float4 a = xr[t], b = xr[t + 256];
        ((float4*)xs[rr])[t] = a;
        ((float4*)xs[rr])[t + 256] = b;
        short4 oa, ob;
        oa.x = f2bf(a.x); oa.y = f2bf(a.y); oa.z = f2bf(a.z); oa.w = f2bf(a.w);
        ob.x = f2bf(b.x); ob.y = f2bf(b.y); ob.z = f2bf(b.z); ob.w = f2bf(b.w);
        short4* xo = (short4*)(xb + (size_t)(m0 + rr) * H_);
        xo[t] = oa;
        xo[t + 256] = ob;
    }
    __syncthreads();
    const int c = t & 15, seg = t >> 4;            // 16 cols x 16 k-segments
    const int kb = seg * 128;
    const float4* W4 = (const float4*)(Wba + (size_t)c * 2048 + kb);
    const float4* x0 = (const float4*)&xs[0][kb];
    const float4* x1 = (const float4*)&xs[1][kb];
    const float4* x2 = (const float4*)&xs[2][kb];
    const float4* x3 = (const float4*)&xs[3][kb];
    float a0 = 0.f, a1 = 0.f, a2 = 0.f, a3 = 0.f;
#pragma unroll 8
    for (int k4 = 0; k4 < 32; k4++) {
        float4 w = W4[k4];
        float4 v0 = x0[k4], v1 = x1[k4], v2 = x2[k4], v3 = x3[k4];
        a0 += w.x * v0.x + w.y * v0.y + w.z * v0.z + w.w * v0.w;
        a1 += w.x * v1.x + w.y * v1.y + w.z * v1.z + w.w * v1.w;
        a2 += w.x * v2.x + w.y * v2.y + w.z * v2.z + w.w * v2.w;
        a3 += w.x * v3.x + w.y * v3.y + w.z * v3.z + w.w * v3.w;
    }
    part[0][t] = a0; part[1][t] = a1; part[2][t] = a2; part[3][t] = a3;
    __syncthreads();
    if (t < 64) {
        int rr = t >> 4, cc = t & 15;
        float s = 0.f;
#pragma unroll
        for (int j = 0; j < 16; j++) s += part[rr][j * 16 + cc];
        bgag[(size_t)(m0 + rr) * 16 + cc] = s;   // [0..8)=bg, [8..16)=ag
    }
}

// ---------------- transpose + convert: W (KxN f32) -> Wt (NxK bf16) ----------------
__global__ __launch_bounds__(256) void k_transpose_cvt(const float* __restrict__ W,
                                                       short* __restrict__ Wt,
                                                       int K, int N) {
    __shared__ float tile[32][33];
    int n0 = blockIdx.x * 32, k0 = blockIdx.y * 32;
    int tx = threadIdx.x, ty = threadIdx.y;   // 32 x 8
#pragma unroll
    for (int i = 0; i < 32; i += 8)
        tile[ty + i][tx] = W[(size_t)(k0 + ty + i) * N + n0 + tx];
    __syncthreads();
#pragma unroll
    for (int i = 0; i < 32; i += 8)
        Wt[(size_t)(n0 + ty + i) * K + k0 + tx] = f2bf(tile[tx][ty + i]);
}

// ---------------- RoPE table: ctab[s][i] = {cos(s*inv_i), sin(s*inv_i)} ----------------
__global__ __launch_bounds__(256) void k_ropetab(float2* __restrict__ ctab) {
    int idx = blockIdx.x * 256 + threadIdx.x;   // S_*64
    int i = idx & 63, s = idx >> 6;
    float inv = exp2f(-(float)i * (2.0f / 128.0f) * 19.931568569324174f);
    float f = (float)s * inv;
    float sn, cs;
    sincosf(f, &sn, &cs);
    ctab[idx] = make_float2(cs, sn);
}

// ========== R8: exact m201 8-phase 256x256 GEMM (8 phases / 2 K-tiles) ==========
// C = A(MxK bf16) * Bt(NxK bf16)^T. BM=BN=256, BK=64, 8 waves (2M x 4N),
// wave tile 128x64. LDS 128KB: buf[p] = A[256][64] + B[256][64] (32KB each),
// kt even->buf0, odd->buf1. Rows are 128B, 8 chunks of 16B; swizzle:
// LDS[row][c] = global[row][c ^ ((row>>1)&7)], read addr uses same XOR ->
// conflict-free ds_read_b128 (uniform 8 lanes/chunk-column) + linear DMA dest.
// Phase = one C-quadrant (4 i-frags x 2 j-frags x 2 k-slices = 16 MFMA):
//   ph1:(b0,i0,j0) ph2:(b0,i0,j1) ph3:(b0,i1,j1) ph4:(b0,i1,j0)
//   ph5-8: same on b1. Frag reads per phase: {12,4,8,4,12,4,8,4}.
// Stage units: A-quarters (64 rows, 8KB, 1 load/thread), B whole (32KB, 4).
//   ph1: B(kt1)->b1   ph2: A02(kt0+2)->b0   ph4: A13(kt0+2)->b0
//   ph5: B(kt0+2)->b0 ph7: A02(kt1+2)->b1   ph8: A13(kt1+2)->b1
// WAR: each staged region's last read is in an earlier phase (A quarters die
// at ph1/ph3 by wave-group; B dies at ph4/ph8), barrier-ordered.
// RAW: vmcnt(4) at ph4 drains {A02,A13,B}(kt1) [issued ph7/ph8 prev iter +
// ph1]; vmcnt(4) at ph8 drains {A02,A13,B}(kt0+2) [ph2/ph4/ph5]. Counted
// vmcnt never 0 in loop. Tail: clamped stages rewrite identical data.
// EPI=0: LDS-staged coalesced f32 C. EPI=1: fused RoPE + packed bf16 C.
#define PH_BEGIN() \
    asm volatile("s_barrier" ::: "memory"); \
    asm volatile("s_waitcnt lgkmcnt(0)" ::: "memory"); \
    __builtin_amdgcn_sched_barrier(0); \
    __builtin_amdgcn_s_setprio(1)
#define PH_END() \
    __builtin_amdgcn_s_setprio(0); \
    asm volatile("s_barrier" ::: "memory")
#define PH_END_V() \
    __builtin_amdgcn_s_setprio(0); \
    asm volatile("s_waitcnt vmcnt(4)" ::: "memory"); \
    asm volatile("s_barrier" ::: "memory")
#define RD_A(P, IH) \
    _Pragma("unroll") for (int f = 0; f < 4; f++) { \
        af[f][0] = *(const bf16x8*)(ArdB + (P) * BUF + (IH) * 8192 + f * 2048 + cb0); \
        af[f][1] = *(const bf16x8*)(ArdB + (P) * BUF + (IH) * 8192 + f * 2048 + cb1); \
    }
#define RD_B(P, JH) \
    _Pragma("unroll") for (int g = 0; g < 2; g++) { \
        bf[g][0] = *(const bf16x8*)(BrdB + (P) * BUF + (JH) * 4096 + g * 2048 + cb0); \
        bf[g][1] = *(const bf16x8*)(BrdB + (P) * BUF + (JH) * 4096 + g * 2048 + cb1); \
    }
#define MF(IH, JH) \
    _Pragma("unroll") for (int f = 0; f < 4; f++) \
    _Pragma("unroll") for (int g = 0; g < 2; g++) { \
        acc[(IH) * 4 + f][(JH) * 2 + g] = __builtin_amdgcn_mfma_f32_16x16x32_bf16( \
            af[f][0], bf[g][0], acc[(IH) * 4 + f][(JH) * 2 + g], 0, 0, 0); \
        acc[(IH) * 4 + f][(JH) * 2 + g] = __builtin_amdgcn_mfma_f32_16x16x32_bf16( \
            af[f][1], bf[g][1], acc[(IH) * 4 + f][(JH) * 2 + g], 0, 0, 0); \
    }

template <int EPI>
__global__ __launch_bounds__(512, 2) void k_gemm8p(const short* __restrict__ A,
                                                   const short* __restrict__ Bt,
                                                   float* __restrict__ Cf,
                                                   unsigned short* __restrict__ Cb,
                                                   const float2* __restrict__ ctab,
                                                   int M, int N, int K) {
    constexpr int BM = 256, BN = 256;
    constexpr int BUF = 65536, BOFF = 32768;
    constexpr int LDSB = (EPI == 0) ? 133120 : 131072;
    __shared__ __align__(16) char lds[LDSB];

    const int t = threadIdx.x;
    const int lane = t & 63, wave = t >> 6;
    const int mrow = lane & 15, kq = lane >> 4;
    const int fr = (mrow >> 1) & 7;
    const int cb0 = (kq ^ fr) * 16;          // ks=0 chunk byte offset
    const int cb1 = ((4 + kq) ^ fr) * 16;    // ks=1

    // XCD-aware bijective swizzle (grid % 8 == 0), bn fastest (B L2 reuse)
    const int nwg = gridDim.x;
    const int w0 = blockIdx.x;
    const int wg = (w0 & 7) * (nwg >> 3) + (w0 >> 3);
    const int NB = N / BN;
    const int bn = (wg % NB) * BN;
    const int bm = (wg / NB) * BM;

    const int wm = (wave >> 2) * 128;
    const int wn = (wave & 3) * 64;

    const short* __restrict__ Ab = A + (size_t)bm * K;
    const short* __restrict__ Bb = Bt + (size_t)bn * K;

    // stage offsets: quarter q (64 rows x 64 cols, 8KB, 1 load/thread);
    // thread t -> row u = t>>3 (within quarter), chunk cA = t&7; global source
    // chunk = cA ^ ((row>>1)&7) so that linear LDS + XOR'd read = identity.
    const int uA = t >> 3, cA = t & 7;
    const int swz = cA ^ ((uA >> 1) & 7);
    size_t gq[4]; int lq[4];
#pragma unroll
    for (int q = 0; q < 4; q++) {
        gq[q] = (size_t)(q * 64 + uA) * K + swz * 8;
        lq[q] = (q * 64 + uA) * 128 + cA * 16;
    }
    auto stA02 = [&](int kt, int p) {
        async_ld16(Ab + gq[0] + kt * 64, lds + p * BUF + lq[0]);
        async_ld16(Ab + gq[2] + kt * 64, lds + p * BUF + lq[2]);
    };
    auto stA13 = [&](int kt, int p) {
        async_ld16(Ab + gq[1] + kt * 64, lds + p * BUF + lq[1]);
        async_ld16(Ab + gq[3] + kt * 64, lds + p * BUF + lq[3]);
    };
    auto stB = [&](int kt, int p) {
#pragma unroll
        for (int q = 0; q < 4; q++)
            async_ld16(Bb + gq[q] + kt * 64, lds + p * BUF + BOFF + lq[q]);
    };

    const char* ArdB = lds + (wm + mrow) * 128;
    const char* BrdB = lds + BOFF + (wn + mrow) * 128;

    f32x4 acc[8][4] = {};
    bf16x8 af[4][2], bf[2][2];

    const int NT = K >> 6;   // even (K=2048 or 1024)

    // ---- prologue: b0 <- kt0 full, b1 <- A quarters of kt1 ----
    stA02(0, 0); stA13(0, 0); stB(0, 0);
    stA02(1, 1); stA13(1, 1);
    asm volatile("s_waitcnt vmcnt(4)" ::: "memory");   // b0 resident
    asm volatile("s_barrier" ::: "memory");

    for (int it = 0; it < (NT >> 1); it++) {
        const int kt1 = 2 * it + 1;
        const int n0 = (2 * it + 2 < NT) ? 2 * it + 2 : NT - 1;
        const int n1 = (2 * it + 3 < NT) ? 2 * it + 3 : NT - 1;

        // ph1: (b0,i0,j0); stage B(kt1)->b1
        RD_A(0, 0); RD_B(0, 0); stB(kt1, 1);
        asm volatile("s_waitcnt lgkmcnt(8)" ::: "memory");
        PH_BEGIN(); MF(0, 0); PH_END();
        // ph2: (b0,i0,j1); stage A02(n0)->b0
        RD_B(0, 1); stA02(n0, 0);
        PH_BEGIN(); MF(0, 1); PH_END();
        // ph3: (b0,i1,j1)
        RD_A(0, 1);
        PH_BEGIN(); MF(1, 1); PH_END();
        // ph4: (b0,i1,j0); stage A13(n0)->b0; drain -> b1 data ready
        RD_B(0, 0); stA13(n0, 0);
        PH_BEGIN(); MF(1, 0); PH_END_V();

        // ph5: (b1,i0,j0); stage B(n0)->b0
        RD_A(1, 0); RD_B(1, 0); stB(n0, 0);
        asm volatile("s_waitcnt lgkmcnt(8)" ::: "memory");
        PH_BEGIN(); MF(0, 0); PH_END();
        // ph6: (b1,i0,j1)
        RD_B(1, 1);
        PH_BEGIN(); MF(0, 1); PH_END();
        // ph7: (b1,i1,j1); stage A02(n1)->b1
        RD_A(1, 1); stA02(n1, 1);
        PH_BEGIN(); MF(1, 1); PH_END();
        // ph8: (b1,i1,j0); stage A13(n1)->b1; drain -> b0 data ready
        RD_B(1, 0); stA13(n1, 1);
        PH_BEGIN(); MF(1, 0); PH_END_V();
    }
    asm volatile("s_waitcnt vmcnt(0)" ::: "memory");

    // ---- epilogue: C/D layout col = lane&15, row = (lane>>4)*4 + reg ----
    const int crow = (lane >> 4) * 4, ccol = lane & 15;
    if (EPI == 0) {
        // LDS-staged coalesced f32 stores, 2 passes of 64 M-rows per half
        float* lf = (float*)lds;
#pragma unroll
        for (int p2 = 0; p2 < 2; p2++) {
            __syncthreads();
#pragma unroll
            for (int i = 0; i < 4; i++) {
                const int ii = p2 * 4 + i;
#pragma unroll
                for (int j = 0; j < 4; j++)
#pragma unroll
                    for (int r = 0; r < 4; r++) {
                        int rl = wm + ii * 16 + crow + r;
                        int slot = (rl & 63) | ((rl >> 7) << 6);
                        lf[slot * 260 + wn + j * 16 + ccol] = acc[ii][j][r];
                    }
            }
            __syncthreads();
#pragma unroll
            for (int rep = 0; rep < 16; rep++) {
                int idx = rep * 512 + t;
                int slot = idx >> 6, c4 = idx & 63;
                int rl = (slot & 63) + p2 * 64 + ((slot >> 6) << 7);
                float4 v = *(const float4*)&lf[slot * 260 + c4 * 4];
                *(float4*)(Cf + (size_t)(bm + rl) * N + bn + c4 * 4) = v;
            }
        }
    } else {
#pragma unroll
        for (int i = 0; i < 8; i++)
#pragma unroll
            for (int j = 0; j < 4; j++) {
                const int col = bn + wn + j * 16 + ccol;
                const int rowb = bm + wm + i * 16 + crow;
                // cols [0,2048) are q|k: RoPE. 16-col tile never straddles the
                // 2048 boundary or a 128 head boundary -> wave-uniform branch.
                const bool qk = col < 2048;
                const int fi = (col & 127) >> 1;
                const bool even = (col & 1) == 0;
                uint32_t* Cd = (uint32_t*)(Cb + ((size_t)rowb * N + (col & ~1)));
#pragma unroll
                for (int r = 0; r < 4; r++) {
                    float v = acc[i][j][r];
                    if (qk) {
                        int s = (rowb + r) & (S_ - 1);
                        float2 cs = ctab[s * 64 + fi];
                        float pp = __shfl_xor(v, 1);
                        v = even ? v * cs.x - pp * cs.y : v * cs.x + pp * cs.y;
                    }
                    int hb = (int)(unsigned short)f2bf(v);
                    int pb = __shfl_xor(hb, 1);
                    if (even)
                        Cd[(size_t)r * (N >> 1)] = (uint32_t)(hb | (pb << 16));
                }
            }
    }
}

// ====== sliding-window attn, 4 rows/block ======
__global__ __launch_bounds__(256) void k_attn4(const unsigned short* __restrict__ qkvz,
                                               const float* __restrict__ bgag,
                                               const float* __restrict__ norm_w,
                                               short* __restrict__ yn) {
    const int m0 = blockIdx.x * 4;
    const int s0 = m0 & (S_ - 1);
    const int t = threadIdx.x;
    __shared__ unsigned short kvls[8][2048];   // cols [1024,3072) = k|v
    __shared__ float sc[4][NH_][5];
    __shared__ float red[4][4];                // [wave][row]

#pragma unroll
    for (int i = 0; i < 8; i++) {
        int g = m0 - 4 + i;
        g = (g < 0) ? 0 : g;                   // only block 0; values unused
        const uint4* src = (const uint4*)(qkvz + (size_t)g * NQKVZ + 1024);
        ((uint4*)kvls[i])[t] = src[t];
    }
    __syncthreads();

    {
        const int r = t >> 6, h = (t >> 3) & 7, l8 = t & 7;
        const int sr = s0 + r;
        const int nOff = (sr < 4 ? sr : 4) + 1;
        float qv[16];
        {
            const unsigned short* qg = qkvz + (size_t)(m0 + r) * NQKVZ + h * 128 + l8 * 16;
#pragma unroll
            for (int d = 0; d < 16; d++) qv[d] = bf2f(qg[d]);
        }
        const float ag = bgag[(size_t)(m0 + r) * 16 + 8 + h];
#pragma unroll
        for (int off = 0; off < 5; off++) {
            float acc = 0.f;
            const unsigned short* kk = kvls[r + 4 - off] + h * 128 + l8 * 16;
#pragma unroll
            for (int d = 0; d < 16; d++) acc += qv[d] * bf2f(kk[d]);
#pragma unroll
            for (int w = 1; w < 8; w <<= 1) acc += __shfl_xor(acc, w);
            if (l8 == 0) {
                float val = 0.f;
                if (off < nOff) {
                    float bg = bgag[(size_t)(m0 + r - off) * 16 + h];
                    float g = 1.f / (1.f + expf(-ag * bg));
                    val = acc * 0.08838834764831845f * g;   // 1/sqrt(128) * gate
                }
                sc[r][h][off] = val;
            }
        }
    }
    __syncthreads();

    const int e0 = t * 4, h2 = t >> 5;
    float yv[4][4], zs[4][4], ssr[4];
    float nw[4];
    {
        const float4 n4 = *(const float4*)(norm_w + e0);
        nw[0] = n4.x; nw[1] = n4.y; nw[2] = n4.z; nw[3] = n4.w;
    }
#pragma unroll
    for (int r = 0; r < 4; r++) {
        const int sr = s0 + r;
        float o[4] = {0.f, 0.f, 0.f, 0.f};
        if (sr == 0) {
#pragma unroll
            for (int d = 0; d < 4; d++) o[d] = bf2f(kvls[r + 4][1024 + e0 + d]);
        } else {
            const int nOff = (sr < 4 ? sr : 4) + 1;
            for (int off = 0; off < nOff; off++) {
                float w = sc[r][h2][off];
#pragma unroll
                for (int d = 0; d < 4; d++)
                    o[d] += w * bf2f(kvls[r + 4 - off][1024 + e0 + d]);
            }
        }
        const unsigned short* zg = qkvz + (size_t)(m0 + r) * NQKVZ + 3072 + e0;
        float ss = 0.f;
#pragma unroll
        for (int d = 0; d < 4; d++) {
            float z = bf2f(zg[d]);
            float sg = 1.f / (1.f + expf(-z));
            yv[r][d] = o[d] * sg;
            zs[r][d] = z * sg;
            ss += yv[r][d] * yv[r][d];
        }
        ssr[r] = ss;
    }
    const int wave = t >> 6, lane = t & 63;
#pragma unroll
    for (int r = 0; r < 4; r++)
#pragma unroll
        for (int w = 1; w < 64; w <<= 1) ssr[r] += __shfl_xor(ssr[r], w);
    if (lane == 0) {
        red[wave][0] = ssr[0]; red[wave][1] = ssr[1];
        red[wave][2] = ssr[2]; red[wave][3] = ssr[3];
    }
    __syncthreads();
#pragma unroll
    for (int r = 0; r < 4; r++) {
        float tot = red[0][r] + red[1][r] + red[2][r] + red[3][r];
        float rinv = 1.f / sqrtf(tot * (1.0f / 1024.0f) + 1e-6f);
        short4 ov;
        ov.x = f2bf(yv[r][0] * rinv * nw[0] * zs[r][0]);
        ov.y = f2bf(yv[r][1] * rinv * nw[1] * zs[r][1]);
        ov.z = f2bf(yv[r][2] * rinv * nw[2] * zs[r][2]);
        ov.w = f2bf(yv[r][3] * rinv * nw[3] * zs[r][3]);
        ((short4*)yn)[(size_t)(m0 + r) * 256 + t] = ov;
    }
}

extern "C" void kernel_launch(void* const* d_in, const int* in_sizes, int n_in,
                              void* d_out, int out_size, void* d_ws, size_t ws_size,
                              hipStream_t stream) {
    const float* x      = (const float*)d_in[0];
    const float* W_qkv  = (const float*)d_in[1];
    const float* W_z    = (const float*)d_in[2];
    const float* W_b    = (const float*)d_in[3];
    const float* W_a    = (const float*)d_in[4];
    const float* norm_w = (const float*)d_in[5];
    const float* W_out  = (const float*)d_in[6];
    float* out = (float*)d_out;

    // workspace (~135 MB)
    char* ws = (char*)d_ws;
    short* xb    = (short*)ws;          ws += (size_t)MR * H_ * 2;       // 32 MB
    short* Wt1   = (short*)ws;          ws += (size_t)NQKVZ * H_ * 2;    // 16 MB
    short* Wt2   = (short*)ws;          ws += (size_t)H_ * KD_ * 2;      //  4 MB
    unsigned short* qkvzb = (unsigned short*)ws; ws += (size_t)MR * NQKVZ * 2; // 64 MB
    float* bgag  = (float*)ws;          ws += (size_t)MR * 16 * 4;       // 0.5 MB
    short* yn    = (short*)ws;          ws += (size_t)MR * KD_ * 2;      // 16 MB
    float2* ctab = (float2*)ws;         ws += (size_t)S_ * 64 * 8;       //  2 MB
    float* Wba   = (float*)ws;          ws += (size_t)16 * 2048 * 4;     // 128 KB

    // 0. transpose W_b|W_a for contiguous reads
    k_wba<<<16 * 2048 / 256, 256, 0, stream>>>(W_b, W_a, Wba);
    // 1. fused convert x->bf16 + bg/ag skinny GEMM (4 rows/block, 4x W reuse)
    k_cvt_bgag4<<<MR / 4, 256, 0, stream>>>(x, xb, Wba, bgag);
    // 2. transpose-convert weights
    k_transpose_cvt<<<dim3(3072 / 32, 2048 / 32), dim3(32, 8), 0, stream>>>(W_qkv, Wt1, 2048, 3072);
    k_transpose_cvt<<<dim3(1024 / 32, 2048 / 32), dim3(32, 8), 0, stream>>>(W_z, Wt1 + (size_t)3072 * 2048, 2048, 1024);
    k_transpose_cvt<<<dim3(2048 / 32, 1024 / 32), dim3(32, 8), 0, stream>>>(W_out, Wt2, 1024, 2048);
    // 3. rope table
    k_ropetab<<<S_ * 64 / 256, 256, 0, stream>>>(ctab);
    // 4. GEMM1 (m201 8-phase 256², fused rope epilogue): qkvz = rope(x @ [W_qkv|W_z])
    k_gemm8p<1><<<(MR / 256) * (NQKVZ / 256), 512, 0, stream>>>(
        xb, Wt1, nullptr, qkvzb, ctab, MR, NQKVZ, H_);
    // 5. attention window + gating + RMSNorm -> yn (bf16), 4 rows/block
    k_attn4<<<MR / 4, 256, 0, stream>>>(qkvzb, bgag, norm_w, yn);
    // 6. GEMM2 (m201 8-phase 256x256, coalesced LDS-staged epilogue): out = yn @ W_out
    k_gemm8p<0><<<(MR / 256) * (H_ / 256), 512, 0, stream>>>(
        yn, Wt2, out, nullptr, nullptr, MR, H_, KD_);
}

// Round 9
// 434.367 us; speedup vs baseline: 1.0907x; 1.0054x over previous
//
#include <hip/hip_runtime.h>
#include <hip/hip_bf16.h>
#include <stdint.h>

#define B_   2
#define S_   4096
#define H_   2048
#define NH_  8
#define D_   128
#define KD_  1024
#define MR   (B_ * S_)          // 8192 rows
#define NQKVZ 4096              // q|k|v|z concatenated width

typedef __attribute__((ext_vector_type(8))) short bf16x8;
typedef __attribute__((ext_vector_type(4))) float f32x4;

__device__ __forceinline__ short f2bf(float f) {
    union { float f; uint32_t u; } v; v.f = f;
    uint32_t r = v.u + 0x7FFF + ((v.u >> 16) & 1);   // RNE
    return (short)(r >> 16);
}
__device__ __forceinline__ float bf2f(unsigned short u) {
    union { uint32_t u; float f; } v; v.u = (uint32_t)u << 16; return v.f;
}

__device__ __forceinline__ void async_ld16(const void* g, void* l) {
    __builtin_amdgcn_global_load_lds(
        (const __attribute__((address_space(1))) uint32_t*)g,
        (__attribute__((address_space(3))) uint32_t*)l, 16, 0, 0);
}

// ---------------- fused prep: RoPE table + W_b|W_a transpose (1 launch) ----------------
__global__ __launch_bounds__(256) void k_prep(float2* __restrict__ ctab,
                                              const float* __restrict__ Wb,
                                              const float* __restrict__ Wa,
                                              float* __restrict__ Wba) {
    const int bid = blockIdx.x, t = threadIdx.x;
    if (bid < 1024) {                              // rope table: S_*64 entries
        int idx = bid * 256 + t;
        int i = idx & 63, s = idx >> 6;
        float inv = exp2f(-(float)i * (2.0f / 128.0f) * 19.931568569324174f);
        float f = (float)s * inv;
        float sn, cs;
        sincosf(f, &sn, &cs);
        ctab[idx] = make_float2(cs, sn);
    } else {                                       // Wba: [16][2048]
        int idx = (bid - 1024) * 256 + t;
        int k = idx & 2047, c = idx >> 11;
        float v = (c < 8) ? Wb[(size_t)k * 8 + c] : Wa[(size_t)k * 8 + (c - 8)];
        Wba[(size_t)c * 2048 + k] = v;
    }
}

// ---------------- fused: 4 x rows -> bf16 + bgag skinny GEMM (4x W reuse) ----------------
__global__ __launch_bounds__(256) void k_cvt_bgag4(const float* __restrict__ x,
                                                   short* __restrict__ xb,
                                                   const float* __restrict__ Wba,
                                                   float* __restrict__ bgag) {
    const int m0 = blockIdx.x * 4, t = threadIdx.x;
    __shared__ float xs[4][2048];
    __shared__ float part[4][256];
#pragma unroll
    for (int rr = 0; rr < 4; rr++) {
        const float4* xr = (const float4*)(x + (size_t)(m0 + rr) * H_);
        float4 a = xr[t], b = xr[t + 256];
        ((float4*)xs[rr])[t] = a;
        ((float4*)xs[rr])[t + 256] = b;
        short4 oa, ob;
        oa.x = f2bf(a.x); oa.y = f2bf(a.y); oa.z = f2bf(a.z); oa.w = f2bf(a.w);
        ob.x = f2bf(b.x); ob.y = f2bf(b.y); ob.z = f2bf(b.z); ob.w = f2bf(b.w);
        short4* xo = (short4*)(xb + (size_t)(m0 + rr) * H_);
        xo[t] = oa;
        xo[t + 256] = ob;
    }
    __syncthreads();
    const int c = t & 15, seg = t >> 4;            // 16 cols x 16 k-segments
    const int kb = seg * 128;
    const float4* W4 = (const float4*)(Wba + (size_t)c * 2048 + kb);
    const float4* x0 = (const float4*)&xs[0][kb];
    const float4* x1 = (const float4*)&xs[1][kb];
    const float4* x2 = (const float4*)&xs[2][kb];
    const float4* x3 = (const float4*)&xs[3][kb];
    float a0 = 0.f, a1 = 0.f, a2 = 0.f, a3 = 0.f;
#pragma unroll 8
    for (int k4 = 0; k4 < 32; k4++) {
        float4 w = W4[k4];
        float4 v0 = x0[k4], v1 = x1[k4], v2 = x2[k4], v3 = x3[k4];
        a0 += w.x * v0.x + w.y * v0.y + w.z * v0.z + w.w * v0.w;
        a1 += w.x * v1.x + w.y * v1.y + w.z * v1.z + w.w * v1.w;
        a2 += w.x * v2.x + w.y * v2.y + w.z * v2.z + w.w * v2.w;
        a3 += w.x * v3.x + w.y * v3.y + w.z * v3.z + w.w * v3.w;
    }
    part[0][t] = a0; part[1][t] = a1; part[2][t] = a2; part[3][t] = a3;
    __syncthreads();
    if (t < 64) {
        int rr = t >> 4, cc = t & 15;
        float s = 0.f;
#pragma unroll
        for (int j = 0; j < 16; j++) s += part[rr][j * 16 + cc];
        bgag[(size_t)(m0 + rr) * 16 + cc] = s;   // [0..8)=bg, [8..16)=ag
    }
}

// ------- all three weight transposes in ONE launch (flat grid, routed) -------
// blocks [0,6144): W_qkv (K2048,N3072); [6144,8192): W_z (K2048,N1024);
// [8192,10240): W_out (K1024,N2048).
__global__ __launch_bounds__(256) void k_transpose_all(const float* __restrict__ Wqkv,
                                                       const float* __restrict__ Wz,
                                                       const float* __restrict__ Wout,
                                                       short* __restrict__ Wt1,
                                                       short* __restrict__ Wt2) {
    __shared__ float tile[32][33];
    const int bid = blockIdx.x;
    const float* W; short* Wt; int K, N, bx, by;
    if (bid < 6144)      { W = Wqkv; Wt = Wt1;                        K = 2048; N = 3072; bx = bid % 96;          by = bid / 96; }
    else if (bid < 8192) { W = Wz;   Wt = Wt1 + (size_t)3072 * 2048;  K = 2048; N = 1024; bx = (bid - 6144) % 32; by = (bid - 6144) / 32; }
    else                 { W = Wout; Wt = Wt2;                        K = 1024; N = 2048; bx = (bid - 8192) % 64; by = (bid - 8192) / 64; }
    const int n0 = bx * 32, k0 = by * 32;
    const int tx = threadIdx.x, ty = threadIdx.y;   // 32 x 8
#pragma unroll
    for (int i = 0; i < 32; i += 8)
        tile[ty + i][tx] = W[(size_t)(k0 + ty + i) * N + n0 + tx];
    __syncthreads();
#pragma unroll
    for (int i = 0; i < 32; i += 8)
        Wt[(size_t)(n0 + ty + i) * K + k0 + tx] = f2bf(tile[tx][ty + i]);
}

// ========== m201 8-phase 256x256 GEMM (FROZEN since R8 — control) ==========
// Full schedule/ledger documentation: see R8 notes. MfmaUtil pinned ~32%
// across 6 schedule variants; K-loop frozen per R7 commitment.
#define PH_BEGIN() \
    asm volatile("s_barrier" ::: "memory"); \
    asm volatile("s_waitcnt lgkmcnt(0)" ::: "memory"); \
    __builtin_amdgcn_sched_barrier(0); \
    __builtin_amdgcn_s_setprio(1)
#define PH_END() \
    __builtin_amdgcn_s_setprio(0); \
    asm volatile("s_barrier" ::: "memory")
#define PH_END_V() \
    __builtin_amdgcn_s_setprio(0); \
    asm volatile("s_waitcnt vmcnt(4)" ::: "memory"); \
    asm volatile("s_barrier" ::: "memory")
#define RD_A(P, IH) \
    _Pragma("unroll") for (int f = 0; f < 4; f++) { \
        af[f][0] = *(const bf16x8*)(ArdB + (P) * BUF + (IH) * 8192 + f * 2048 + cb0); \
        af[f][1] = *(const bf16x8*)(ArdB + (P) * BUF + (IH) * 8192 + f * 2048 + cb1); \
    }
#define RD_B(P, JH) \
    _Pragma("unroll") for (int g = 0; g < 2; g++) { \
        bf[g][0] = *(const bf16x8*)(BrdB + (P) * BUF + (JH) * 4096 + g * 2048 + cb0); \
        bf[g][1] = *(const bf16x8*)(BrdB + (P) * BUF + (JH) * 4096 + g * 2048 + cb1); \
    }
#define MF(IH, JH) \
    _Pragma("unroll") for (int f = 0; f < 4; f++) \
    _Pragma("unroll") for (int g = 0; g < 2; g++) { \
        acc[(IH) * 4 + f][(JH) * 2 + g] = __builtin_amdgcn_mfma_f32_16x16x32_bf16( \
            af[f][0], bf[g][0], acc[(IH) * 4 + f][(JH) * 2 + g], 0, 0, 0); \
        acc[(IH) * 4 + f][(JH) * 2 + g] = __builtin_amdgcn_mfma_f32_16x16x32_bf16( \
            af[f][1], bf[g][1], acc[(IH) * 4 + f][(JH) * 2 + g], 0, 0, 0); \
    }

template <int EPI>
__global__ __launch_bounds__(512, 2) void k_gemm8p(const short* __restrict__ A,
                                                   const short* __restrict__ Bt,
                                                   float* __restrict__ Cf,
                                                   unsigned short* __restrict__ Cb,
                                                   const float2* __restrict__ ctab,
                                                   int M, int N, int K) {
    constexpr int BM = 256, BN = 256;
    constexpr int BUF = 65536, BOFF = 32768;
    constexpr int LDSB = (EPI == 0) ? 133120 : 131072;
    __shared__ __align__(16) char lds[LDSB];

    const int t = threadIdx.x;
    const int lane = t & 63, wave = t >> 6;
    const int mrow = lane & 15, kq = lane >> 4;
    const int fr = (mrow >> 1) & 7;
    const int cb0 = (kq ^ fr) * 16;
    const int cb1 = ((4 + kq) ^ fr) * 16;

    const int nwg = gridDim.x;
    const int w0 = blockIdx.x;
    const int wg = (w0 & 7) * (nwg >> 3) + (w0 >> 3);
    const int NB = N / BN;
    const int bn = (wg % NB) * BN;
    const int bm = (wg / NB) * BM;

    const int wm = (wave >> 2) * 128;
    const int wn = (wave & 3) * 64;

    const short* __restrict__ Ab = A + (size_t)bm * K;
    const short* __restrict__ Bb = Bt + (size_t)bn * K;

    const int uA = t >> 3, cA = t & 7;
    const int swz = cA ^ ((uA >> 1) & 7);
    size_t gq[4]; int lq[4];
#pragma unroll
    for (int q = 0; q < 4; q++) {
        gq[q] = (size_t)(q * 64 + uA) * K + swz * 8;
        lq[q] = (q * 64 + uA) * 128 + cA * 16;
    }
    auto stA02 = [&](int kt, int p) {
        async_ld16(Ab + gq[0] + kt * 64, lds + p * BUF + lq[0]);
        async_ld16(Ab + gq[2] + kt * 64, lds + p * BUF + lq[2]);
    };
    auto stA13 = [&](int kt, int p) {
        async_ld16(Ab + gq[1] + kt * 64, lds + p * BUF + lq[1]);
        async_ld16(Ab + gq[3] + kt * 64, lds + p * BUF + lq[3]);
    };
    auto stB = [&](int kt, int p) {
#pragma unroll
        for (int q = 0; q < 4; q++)
            async_ld16(Bb + gq[q] + kt * 64, lds + p * BUF + BOFF + lq[q]);
    };

    const char* ArdB = lds + (wm + mrow) * 128;
    const char* BrdB = lds + BOFF + (wn + mrow) * 128;

    f32x4 acc[8][4] = {};
    bf16x8 af[4][2], bf[2][2];

    const int NT = K >> 6;

    stA02(0, 0); stA13(0, 0); stB(0, 0);
    stA02(1, 1); stA13(1, 1);
    asm volatile("s_waitcnt vmcnt(4)" ::: "memory");
    asm volatile("s_barrier" ::: "memory");

    for (int it = 0; it < (NT >> 1); it++) {
        const int kt1 = 2 * it + 1;
        const int n0 = (2 * it + 2 < NT) ? 2 * it + 2 : NT - 1;
        const int n1 = (2 * it + 3 < NT) ? 2 * it + 3 : NT - 1;

        RD_A(0, 0); RD_B(0, 0); stB(kt1, 1);
        asm volatile("s_waitcnt lgkmcnt(8)" ::: "memory");
        PH_BEGIN(); MF(0, 0); PH_END();
        RD_B(0, 1); stA02(n0, 0);
        PH_BEGIN(); MF(0, 1); PH_END();
        RD_A(0, 1);
        PH_BEGIN(); MF(1, 1); PH_END();
        RD_B(0, 0); stA13(n0, 0);
        PH_BEGIN(); MF(1, 0); PH_END_V();

        RD_A(1, 0); RD_B(1, 0); stB(n0, 0);
        asm volatile("s_waitcnt lgkmcnt(8)" ::: "memory");
        PH_BEGIN(); MF(0, 0); PH_END();
        RD_B(1, 1);
        PH_BEGIN(); MF(0, 1); PH_END();
        RD_A(1, 1); stA02(n1, 1);
        PH_BEGIN(); MF(1, 1); PH_END();
        RD_B(1, 0); stA13(n1, 1);
        PH_BEGIN(); MF(1, 0); PH_END_V();
    }
    asm volatile("s_waitcnt vmcnt(0)" ::: "memory");

    const int crow = (lane >> 4) * 4, ccol = lane & 15;
    if (EPI == 0) {
        float* lf = (float*)lds;
#pragma unroll
        for (int p2 = 0; p2 < 2; p2++) {
            __syncthreads();
#pragma unroll
            for (int i = 0; i < 4; i++) {
                const int ii = p2 * 4 + i;
#pragma unroll
                for (int j = 0; j < 4; j++)
#pragma unroll
                    for (int r = 0; r < 4; r++) {
                        int rl = wm + ii * 16 + crow + r;
                        int slot = (rl & 63) | ((rl >> 7) << 6);
                        lf[slot * 260 + wn + j * 16 + ccol] = acc[ii][j][r];
                    }
            }
            __syncthreads();
#pragma unroll
            for (int rep = 0; rep < 16; rep++) {
                int idx = rep * 512 + t;
                int slot = idx >> 6, c4 = idx & 63;
                int rl = (slot & 63) + p2 * 64 + ((slot >> 6) << 7);
                float4 v = *(const float4*)&lf[slot * 260 + c4 * 4];
                *(float4*)(Cf + (size_t)(bm + rl) * N + bn + c4 * 4) = v;
            }
        }
    } else {
#pragma unroll
        for (int i = 0; i < 8; i++)
#pragma unroll
            for (int j = 0; j < 4; j++) {
                const int col = bn + wn + j * 16 + ccol;
                const int rowb = bm + wm + i * 16 + crow;
                const bool qk = col < 2048;
                const int fi = (col & 127) >> 1;
                const bool even = (col & 1) == 0;
                uint32_t* Cd = (uint32_t*)(Cb + ((size_t)rowb * N + (col & ~1)));
#pragma unroll
                for (int r = 0; r < 4; r++) {
                    float v = acc[i][j][r];
                    if (qk) {
                        int s = (rowb + r) & (S_ - 1);
                        float2 cs = ctab[s * 64 + fi];
                        float pp = __shfl_xor(v, 1);
                        v = even ? v * cs.x - pp * cs.y : v * cs.x + pp * cs.y;
                    }
                    int hb = (int)(unsigned short)f2bf(v);
                    int pb = __shfl_xor(hb, 1);
                    if (even)
                        Cd[(size_t)r * (N >> 1)] = (uint32_t)(hb | (pb << 16));
                }
            }
    }
}

// ====== R9: sliding-window attn, 8 rows/block (1.5 KV loads/output) ======
// kvls ring holds global rows m0-4..m0+7 (12 rows). Boundary: row r consumes
// ring idx r+4-off with off <= min(s0+r,4) <= r at sequence starts => idx>=4,
// clamped rows 0..3 never read. 49.5 KB LDS -> 3 blocks/CU.
__global__ __launch_bounds__(256) void k_attn8(const unsigned short* __restrict__ qkvz,
                                               const float* __restrict__ bgag,
                                               const float* __restrict__ norm_w,
                                               short* __restrict__ yn) {
    const int m0 = blockIdx.x * 8;
    const int s0 = m0 & (S_ - 1);
    const int t = threadIdx.x;
    __shared__ unsigned short kvls[12][2048];  // cols [1024,3072) = k|v
    __shared__ float sc[8][NH_][5];
    __shared__ float red[4][8];                // [wave][row]

#pragma unroll
    for (int i = 0; i < 12; i++) {
        int g = m0 - 4 + i;
        g = (g < 0) ? 0 : g;                   // only first block; never consumed
        const uint4* src = (const uint4*)(qkvz + (size_t)g * NQKVZ + 1024);
        ((uint4*)kvls[i])[t] = src[t];
    }
    __syncthreads();

    // scores: 2 passes of the (4-row x 8-head x 8-lane) mapping
#pragma unroll
    for (int half = 0; half < 2; half++) {
        const int r = (t >> 6) + half * 4;
        const int h = (t >> 3) & 7, l8 = t & 7;
        const int sr = s0 + r;
        const int nOff = (sr < 4 ? sr : 4) + 1;
        float qv[16];
        {
            const unsigned short* qg = qkvz + (size_t)(m0 + r) * NQKVZ + h * 128 + l8 * 16;
#pragma unroll
            for (int d = 0; d < 16; d++) qv[d] = bf2f(qg[d]);
        }
        const float ag = bgag[(size_t)(m0 + r) * 16 + 8 + h];
#pragma unroll
        for (int off = 0; off < 5; off++) {
            float acc = 0.f;
            const unsigned short* kk = kvls[r + 4 - off] + h * 128 + l8 * 16;
#pragma unroll
            for (int d = 0; d < 16; d++) acc += qv[d] * bf2f(kk[d]);
#pragma unroll
            for (int w = 1; w < 8; w <<= 1) acc += __shfl_xor(acc, w);
            if (l8 == 0) {
                float val = 0.f;
                if (off < nOff) {
                    float bg = bgag[(size_t)(m0 + r - off) * 16 + h];
                    float g = 1.f / (1.f + expf(-ag * bg));
                    val = acc * 0.08838834764831845f * g;   // 1/sqrt(128) * gate
                }
                sc[r][h][off] = val;
            }
        }
    }
    __syncthreads();

    // phase 2: thread t covers elements e0..e0+3 of each of the 8 rows
    const int e0 = t * 4, h2 = t >> 5;
    float yv[8][4], zs[8][4], ssr[8];
    float nw[4];
    {
        const float4 n4 = *(const float4*)(norm_w + e0);
        nw[0] = n4.x; nw[1] = n4.y; nw[2] = n4.z; nw[3] = n4.w;
    }
#pragma unroll
    for (int r = 0; r < 8; r++) {
        const int sr = s0 + r;
        float o[4] = {0.f, 0.f, 0.f, 0.f};
        if (sr == 0) {
#pragma unroll
            for (int d = 0; d < 4; d++) o[d] = bf2f(kvls[r + 4][1024 + e0 + d]);
        } else {
            const int nOff = (sr < 4 ? sr : 4) + 1;
            for (int off = 0; off < nOff; off++) {
                float w = sc[r][h2][off];
#pragma unroll
                for (int d = 0; d < 4; d++)
                    o[d] += w * bf2f(kvls[r + 4 - off][1024 + e0 + d]);
            }
        }
        const unsigned short* zg = qkvz + (size_t)(m0 + r) * NQKVZ + 3072 + e0;
        float ss = 0.f;
#pragma unroll
        for (int d = 0; d < 4; d++) {
            float z = bf2f(zg[d]);
            float sg = 1.f / (1.f + expf(-z));
            yv[r][d] = o[d] * sg;
            zs[r][d] = z * sg;
            ss += yv[r][d] * yv[r][d];
        }
        ssr[r] = ss;
    }
    const int wave = t >> 6, lane = t & 63;
#pragma unroll
    for (int r = 0; r < 8; r++)
#pragma unroll
        for (int w = 1; w < 64; w <<= 1) ssr[r] += __shfl_xor(ssr[r], w);
    if (lane == 0) {
#pragma unroll
        for (int r = 0; r < 8; r++) red[wave][r] = ssr[r];
    }
    __syncthreads();
#pragma unroll
    for (int r = 0; r < 8; r++) {
        float tot = red[0][r] + red[1][r] + red[2][r] + red[3][r];
        float rinv = 1.f / sqrtf(tot * (1.0f / 1024.0f) + 1e-6f);
        short4 ov;
        ov.x = f2bf(yv[r][0] * rinv * nw[0] * zs[r][0]);
        ov.y = f2bf(yv[r][1] * rinv * nw[1] * zs[r][1]);
        ov.z = f2bf(yv[r][2] * rinv * nw[2] * zs[r][2]);
        ov.w = f2bf(yv[r][3] * rinv * nw[3] * zs[r][3]);
        ((short4*)yn)[(size_t)(m0 + r) * 256 + t] = ov;
    }
}

extern "C" void kernel_launch(void* const* d_in, const int* in_sizes, int n_in,
                              void* d_out, int out_size, void* d_ws, size_t ws_size,
                              hipStream_t stream) {
    const float* x      = (const float*)d_in[0];
    const float* W_qkv  = (const float*)d_in[1];
    const float* W_z    = (const float*)d_in[2];
    const float* W_b    = (const float*)d_in[3];
    const float* W_a    = (const float*)d_in[4];
    const float* norm_w = (const float*)d_in[5];
    const float* W_out  = (const float*)d_in[6];
    float* out = (float*)d_out;

    // workspace (~135 MB)
    char* ws = (char*)d_ws;
    short* xb    = (short*)ws;          ws += (size_t)MR * H_ * 2;       // 32 MB
    short* Wt1   = (short*)ws;          ws += (size_t)NQKVZ * H_ * 2;    // 16 MB
    short* Wt2   = (short*)ws;          ws += (size_t)H_ * KD_ * 2;      //  4 MB
    unsigned short* qkvzb = (unsigned short*)ws; ws += (size_t)MR * NQKVZ * 2; // 64 MB
    float* bgag  = (float*)ws;          ws += (size_t)MR * 16 * 4;       // 0.5 MB
    short* yn    = (short*)ws;          ws += (size_t)MR * KD_ * 2;      // 16 MB
    float2* ctab = (float2*)ws;         ws += (size_t)S_ * 64 * 8;       //  2 MB
    float* Wba   = (float*)ws;          ws += (size_t)16 * 2048 * 4;     // 128 KB

    // 1. prep: rope table + W_b|W_a transpose (one launch)
    k_prep<<<1024 + 128, 256, 0, stream>>>(ctab, W_b, W_a, Wba);
    // 2. fused convert x->bf16 + bg/ag skinny GEMM (4 rows/block, 4x W reuse)
    k_cvt_bgag4<<<MR / 4, 256, 0, stream>>>(x, xb, Wba, bgag);
    // 3. all weight transposes (one launch)
    k_transpose_all<<<6144 + 2048 + 2048, dim3(32, 8), 0, stream>>>(
        W_qkv, W_z, W_out, Wt1, Wt2);
    // 4. GEMM1 (8-phase 256², fused rope epilogue): qkvz = rope(x @ [W_qkv|W_z])
    k_gemm8p<1><<<(MR / 256) * (NQKVZ / 256), 512, 0, stream>>>(
        xb, Wt1, nullptr, qkvzb, ctab, MR, NQKVZ, H_);
    // 5. attention window + gating + RMSNorm -> yn (bf16), 8 rows/block
    k_attn8<<<MR / 8, 256, 0, stream>>>(qkvzb, bgag, norm_w, yn);
    // 6. GEMM2 (8-phase 256x256, coalesced LDS-staged epilogue): out = yn @ W_out
    k_gemm8p<0><<<(MR / 256) * (H_ / 256), 512, 0, stream>>>(
        yn, Wt2, out, nullptr, nullptr, MR, H_, KD_);
}

// Round 10
// 395.549 us; speedup vs baseline: 1.1977x; 1.0981x over previous
//
#include <hip/hip_runtime.h>
#include <hip/hip_bf16.h>
#include <stdint.h>

#define B_   2
#define S_   4096
#define H_   2048
#define NH_  8
#define D_   128
#define KD_  1024
#define MR   (B_ * S_)          // 8192 rows
#define NQKVZ 4096              // q|k|v|z concatenated width

typedef __attribute__((ext_vector_type(8))) short bf16x8;
typedef __attribute__((ext_vector_type(4))) float f32x4;

__device__ __forceinline__ short f2bf(float f) {
    union { float f; uint32_t u; } v; v.f = f;
    uint32_t r = v.u + 0x7FFF + ((v.u >> 16) & 1);   // RNE
    return (short)(r >> 16);
}
__device__ __forceinline__ float bf2f(unsigned short u) {
    union { uint32_t u; float f; } v; v.u = (uint32_t)u << 16; return v.f;
}

__device__ __forceinline__ void async_ld16(const void* g, void* l) {
    __builtin_amdgcn_global_load_lds(
        (const __attribute__((address_space(1))) uint32_t*)g,
        (__attribute__((address_space(3))) uint32_t*)l, 16, 0, 0);
}

// ================== R10: ONE prep launch (transpose | rope | cvt+bgag) ==================
// Independent sections, flat block routing; removes 3 inter-dispatch gaps and
// lets memory-bound transposes co-schedule with VALU-bound cvt.
//  blocks [0,6144):      W_qkv transpose (K2048,N3072)
//  blocks [6144,8192):   W_z transpose   (K2048,N1024)
//  blocks [8192,10240):  W_out transpose (K1024,N2048)
//  blocks [10240,11264): RoPE table
//  blocks [11264,13312): x->bf16 + bg/ag skinny GEMM (4 rows/block, W direct)
__global__ __launch_bounds__(256) void k_mega(const float* __restrict__ Wqkv,
                                              const float* __restrict__ Wz,
                                              const float* __restrict__ Wout,
                                              short* __restrict__ Wt1,
                                              short* __restrict__ Wt2,
                                              float2* __restrict__ ctab,
                                              const float* __restrict__ x,
                                              short* __restrict__ xb,
                                              const float* __restrict__ Wb,
                                              const float* __restrict__ Wa,
                                              float* __restrict__ bgag) {
    __shared__ __align__(16) char smem[36864];   // max(transpose 4.2K, cvt 36.9K)
    const int bid = blockIdx.x, t = threadIdx.x;

    if (bid < 10240) {
        // ---- weight transpose+convert ----
        float (*tile)[33] = (float(*)[33])smem;
        const float* W; short* Wt; int K, N, bx, by;
        if (bid < 6144)      { W = Wqkv; Wt = Wt1;                       K = 2048; N = 3072; bx = bid % 96;          by = bid / 96; }
        else if (bid < 8192) { W = Wz;   Wt = Wt1 + (size_t)3072 * 2048; K = 2048; N = 1024; bx = (bid - 6144) % 32; by = (bid - 6144) / 32; }
        else                 { W = Wout; Wt = Wt2;                       K = 1024; N = 2048; bx = (bid - 8192) % 64; by = (bid - 8192) / 64; }
        const int n0 = bx * 32, k0 = by * 32;
        const int tx = t & 31, ty = t >> 5;   // 32 x 8
#pragma unroll
        for (int i = 0; i < 32; i += 8)
            tile[ty + i][tx] = W[(size_t)(k0 + ty + i) * N + n0 + tx];
        __syncthreads();
#pragma unroll
        for (int i = 0; i < 32; i += 8)
            Wt[(size_t)(n0 + ty + i) * K + k0 + tx] = f2bf(tile[tx][ty + i]);
    } else if (bid < 11264) {
        // ---- RoPE table ----
        int idx = (bid - 10240) * 256 + t;
        int i = idx & 63, s = idx >> 6;
        float inv = exp2f(-(float)i * (2.0f / 128.0f) * 19.931568569324174f);
        float f = (float)s * inv;
        float sn, cs;
        sincosf(f, &sn, &cs);
        ctab[idx] = make_float2(cs, sn);
    } else {
        // ---- x -> bf16 + bg/ag skinny GEMM, 4 rows/block ----
        float (*xs)[2048] = (float(*)[2048])smem;
        float (*part)[256] = (float(*)[256])(smem + 32768);
        const int m0 = (bid - 11264) * 4;
#pragma unroll
        for (int rr = 0; rr < 4; rr++) {
            const float4* xr = (const float4*)(x + (size_t)(m0 + rr) * H_);
            float4 a = xr[t], b = xr[t + 256];
            ((float4*)xs[rr])[t] = a;
            ((float4*)xs[rr])[t + 256] = b;
            short4 oa, ob;
            oa.x = f2bf(a.x); oa.y = f2bf(a.y); oa.z = f2bf(a.z); oa.w = f2bf(a.w);
            ob.x = f2bf(b.x); ob.y = f2bf(b.y); ob.z = f2bf(b.z); ob.w = f2bf(b.w);
            short4* xo = (short4*)(xb + (size_t)(m0 + rr) * H_);
            xo[t] = oa;
            xo[t + 256] = ob;
        }
        __syncthreads();
        const int c = t & 15, seg = t >> 4;        // 16 cols x 16 k-segments
        const int kb = seg * 128;
        const float* W = (c < 8) ? Wb : Wa;        // 128KB total, L2-resident
        const int cc = c & 7;
        float a0 = 0.f, a1 = 0.f, a2 = 0.f, a3 = 0.f;
#pragma unroll 8
        for (int k = 0; k < 128; k++) {
            float w = W[(size_t)(kb + k) * 8 + cc];
            a0 += w * xs[0][kb + k];
            a1 += w * xs[1][kb + k];
            a2 += w * xs[2][kb + k];
            a3 += w * xs[3][kb + k];
        }
        part[0][t] = a0; part[1][t] = a1; part[2][t] = a2; part[3][t] = a3;
        __syncthreads();
        if (t < 64) {
            int rr = t >> 4, ccx = t & 15;
            float s = 0.f;
#pragma unroll
            for (int j = 0; j < 16; j++) s += part[rr][j * 16 + ccx];
            bgag[(size_t)(m0 + rr) * 16 + ccx] = s;   // [0..8)=bg, [8..16)=ag
        }
    }
}

// ========== m201 8-phase 256x256 GEMM (FROZEN since R8 — control) ==========
#define PH_BEGIN() \
    asm volatile("s_barrier" ::: "memory"); \
    asm volatile("s_waitcnt lgkmcnt(0)" ::: "memory"); \
    __builtin_amdgcn_sched_barrier(0); \
    __builtin_amdgcn_s_setprio(1)
#define PH_END() \
    __builtin_amdgcn_s_setprio(0); \
    asm volatile("s_barrier" ::: "memory")
#define PH_END_V() \
    __builtin_amdgcn_s_setprio(0); \
    asm volatile("s_waitcnt vmcnt(4)" ::: "memory"); \
    asm volatile("s_barrier" ::: "memory")
#define RD_A(P, IH) \
    _Pragma("unroll") for (int f = 0; f < 4; f++) { \
        af[f][0] = *(const bf16x8*)(ArdB + (P) * BUF + (IH) * 8192 + f * 2048 + cb0); \
        af[f][1] = *(const bf16x8*)(ArdB + (P) * BUF + (IH) * 8192 + f * 2048 + cb1); \
    }
#define RD_B(P, JH) \
    _Pragma("unroll") for (int g = 0; g < 2; g++) { \
        bf[g][0] = *(const bf16x8*)(BrdB + (P) * BUF + (JH) * 4096 + g * 2048 + cb0); \
        bf[g][1] = *(const bf16x8*)(BrdB + (P) * BUF + (JH) * 4096 + g * 2048 + cb1); \
    }
#define MF(IH, JH) \
    _Pragma("unroll") for (int f = 0; f < 4; f++) \
    _Pragma("unroll") for (int g = 0; g < 2; g++) { \
        acc[(IH) * 4 + f][(JH) * 2 + g] = __builtin_amdgcn_mfma_f32_16x16x32_bf16( \
            af[f][0], bf[g][0], acc[(IH) * 4 + f][(JH) * 2 + g], 0, 0, 0); \
        acc[(IH) * 4 + f][(JH) * 2 + g] = __builtin_amdgcn_mfma_f32_16x16x32_bf16( \
            af[f][1], bf[g][1], acc[(IH) * 4 + f][(JH) * 2 + g], 0, 0, 0); \
    }

template <int EPI>
__global__ __launch_bounds__(512, 2) void k_gemm8p(const short* __restrict__ A,
                                                   const short* __restrict__ Bt,
                                                   float* __restrict__ Cf,
                                                   unsigned short* __restrict__ Cb,
                                                   const float2* __restrict__ ctab,
                                                   int M, int N, int K) {
    constexpr int BM = 256, BN = 256;
    constexpr int BUF = 65536, BOFF = 32768;
    constexpr int LDSB = (EPI == 0) ? 133120 : 131072;
    __shared__ __align__(16) char lds[LDSB];

    const int t = threadIdx.x;
    const int lane = t & 63, wave = t >> 6;
    const int mrow = lane & 15, kq = lane >> 4;
    const int fr = (mrow >> 1) & 7;
    const int cb0 = (kq ^ fr) * 16;
    const int cb1 = ((4 + kq) ^ fr) * 16;

    const int nwg = gridDim.x;
    const int w0 = blockIdx.x;
    const int wg = (w0 & 7) * (nwg >> 3) + (w0 >> 3);
    const int NB = N / BN;
    const int bn = (wg % NB) * BN;
    const int bm = (wg / NB) * BM;

    const int wm = (wave >> 2) * 128;
    const int wn = (wave & 3) * 64;

    const short* __restrict__ Ab = A + (size_t)bm * K;
    const short* __restrict__ Bb = Bt + (size_t)bn * K;

    const int uA = t >> 3, cA = t & 7;
    const int swz = cA ^ ((uA >> 1) & 7);
    size_t gq[4]; int lq[4];
#pragma unroll
    for (int q = 0; q < 4; q++) {
        gq[q] = (size_t)(q * 64 + uA) * K + swz * 8;
        lq[q] = (q * 64 + uA) * 128 + cA * 16;
    }
    auto stA02 = [&](int kt, int p) {
        async_ld16(Ab + gq[0] + kt * 64, lds + p * BUF + lq[0]);
        async_ld16(Ab + gq[2] + kt * 64, lds + p * BUF + lq[2]);
    };
    auto stA13 = [&](int kt, int p) {
        async_ld16(Ab + gq[1] + kt * 64, lds + p * BUF + lq[1]);
        async_ld16(Ab + gq[3] + kt * 64, lds + p * BUF + lq[3]);
    };
    auto stB = [&](int kt, int p) {
#pragma unroll
        for (int q = 0; q < 4; q++)
            async_ld16(Bb + gq[q] + kt * 64, lds + p * BUF + BOFF + lq[q]);
    };

    const char* ArdB = lds + (wm + mrow) * 128;
    const char* BrdB = lds + BOFF + (wn + mrow) * 128;

    f32x4 acc[8][4] = {};
    bf16x8 af[4][2], bf[2][2];

    const int NT = K >> 6;

    stA02(0, 0); stA13(0, 0); stB(0, 0);
    stA02(1, 1); stA13(1, 1);
    asm volatile("s_waitcnt vmcnt(4)" ::: "memory");
    asm volatile("s_barrier" ::: "memory");

    for (int it = 0; it < (NT >> 1); it++) {
        const int kt1 = 2 * it + 1;
        const int n0 = (2 * it + 2 < NT) ? 2 * it + 2 : NT - 1;
        const int n1 = (2 * it + 3 < NT) ? 2 * it + 3 : NT - 1;

        RD_A(0, 0); RD_B(0, 0); stB(kt1, 1);
        asm volatile("s_waitcnt lgkmcnt(8)" ::: "memory");
        PH_BEGIN(); MF(0, 0); PH_END();
        RD_B(0, 1); stA02(n0, 0);
        PH_BEGIN(); MF(0, 1); PH_END();
        RD_A(0, 1);
        PH_BEGIN(); MF(1, 1); PH_END();
        RD_B(0, 0); stA13(n0, 0);
        PH_BEGIN(); MF(1, 0); PH_END_V();

        RD_A(1, 0); RD_B(1, 0); stB(n0, 0);
        asm volatile("s_waitcnt lgkmcnt(8)" ::: "memory");
        PH_BEGIN(); MF(0, 0); PH_END();
        RD_B(1, 1);
        PH_BEGIN(); MF(0, 1); PH_END();
        RD_A(1, 1); stA02(n1, 1);
        PH_BEGIN(); MF(1, 1); PH_END();
        RD_B(1, 0); stA13(n1, 1);
        PH_BEGIN(); MF(1, 0); PH_END_V();
    }
    asm volatile("s_waitcnt vmcnt(0)" ::: "memory");

    const int crow = (lane >> 4) * 4, ccol = lane & 15;
    if (EPI == 0) {
        float* lf = (float*)lds;
#pragma unroll
        for (int p2 = 0; p2 < 2; p2++) {
            __syncthreads();
#pragma unroll
            for (int i = 0; i < 4; i++) {
                const int ii = p2 * 4 + i;
#pragma unroll
                for (int j = 0; j < 4; j++)
#pragma unroll
                    for (int r = 0; r < 4; r++) {
                        int rl = wm + ii * 16 + crow + r;
                        int slot = (rl & 63) | ((rl >> 7) << 6);
                        lf[slot * 260 + wn + j * 16 + ccol] = acc[ii][j][r];
                    }
            }
            __syncthreads();
#pragma unroll
            for (int rep = 0; rep < 16; rep++) {
                int idx = rep * 512 + t;
                int slot = idx >> 6, c4 = idx & 63;
                int rl = (slot & 63) + p2 * 64 + ((slot >> 6) << 7);
                float4 v = *(const float4*)&lf[slot * 260 + c4 * 4];
                *(float4*)(Cf + (size_t)(bm + rl) * N + bn + c4 * 4) = v;
            }
        }
    } else {
#pragma unroll
        for (int i = 0; i < 8; i++)
#pragma unroll
            for (int j = 0; j < 4; j++) {
                const int col = bn + wn + j * 16 + ccol;
                const int rowb = bm + wm + i * 16 + crow;
                const bool qk = col < 2048;
                const int fi = (col & 127) >> 1;
                const bool even = (col & 1) == 0;
                uint32_t* Cd = (uint32_t*)(Cb + ((size_t)rowb * N + (col & ~1)));
#pragma unroll
                for (int r = 0; r < 4; r++) {
                    float v = acc[i][j][r];
                    if (qk) {
                        int s = (rowb + r) & (S_ - 1);
                        float2 cs = ctab[s * 64 + fi];
                        float pp = __shfl_xor(v, 1);
                        v = even ? v * cs.x - pp * cs.y : v * cs.x + pp * cs.y;
                    }
                    int hb = (int)(unsigned short)f2bf(v);
                    int pb = __shfl_xor(hb, 1);
                    if (even)
                        Cd[(size_t)r * (N >> 1)] = (uint32_t)(hb | (pb << 16));
                }
            }
    }
}

// ====== sliding-window attn, 8 rows/block (FROZEN since R9 — control) ======
__global__ __launch_bounds__(256) void k_attn8(const unsigned short* __restrict__ qkvz,
                                               const float* __restrict__ bgag,
                                               const float* __restrict__ norm_w,
                                               short* __restrict__ yn) {
    const int m0 = blockIdx.x * 8;
    const int s0 = m0 & (S_ - 1);
    const int t = threadIdx.x;
    __shared__ unsigned short kvls[12][2048];  // cols [1024,3072) = k|v
    __shared__ float sc[8][NH_][5];
    __shared__ float red[4][8];                // [wave][row]

#pragma unroll
    for (int i = 0; i < 12; i++) {
        int g = m0 - 4 + i;
        g = (g < 0) ? 0 : g;                   // only first block; never consumed
        const uint4* src = (const uint4*)(qkvz + (size_t)g * NQKVZ + 1024);
        ((uint4*)kvls[i])[t] = src[t];
    }
    __syncthreads();

#pragma unroll
    for (int half = 0; half < 2; half++) {
        const int r = (t >> 6) + half * 4;
        const int h = (t >> 3) & 7, l8 = t & 7;
        const int sr = s0 + r;
        const int nOff = (sr < 4 ? sr : 4) + 1;
        float qv[16];
        {
            const unsigned short* qg = qkvz + (size_t)(m0 + r) * NQKVZ + h * 128 + l8 * 16;
#pragma unroll
            for (int d = 0; d < 16; d++) qv[d] = bf2f(qg[d]);
        }
        const float ag = bgag[(size_t)(m0 + r) * 16 + 8 + h];
#pragma unroll
        for (int off = 0; off < 5; off++) {
            float acc = 0.f;
            const unsigned short* kk = kvls[r + 4 - off] + h * 128 + l8 * 16;
#pragma unroll
            for (int d = 0; d < 16; d++) acc += qv[d] * bf2f(kk[d]);
#pragma unroll
            for (int w = 1; w < 8; w <<= 1) acc += __shfl_xor(acc, w);
            if (l8 == 0) {
                float val = 0.f;
                if (off < nOff) {
                    float bg = bgag[(size_t)(m0 + r - off) * 16 + h];
                    float g = 1.f / (1.f + expf(-ag * bg));
                    val = acc * 0.08838834764831845f * g;   // 1/sqrt(128) * gate
                }
                sc[r][h][off] = val;
            }
        }
    }
    __syncthreads();

    const int e0 = t * 4, h2 = t >> 5;
    float yv[8][4], zs[8][4], ssr[8];
    float nw[4];
    {
        const float4 n4 = *(const float4*)(norm_w + e0);
        nw[0] = n4.x; nw[1] = n4.y; nw[2] = n4.z; nw[3] = n4.w;
    }
#pragma unroll
    for (int r = 0; r < 8; r++) {
        const int sr = s0 + r;
        float o[4] = {0.f, 0.f, 0.f, 0.f};
        if (sr == 0) {
#pragma unroll
            for (int d = 0; d < 4; d++) o[d] = bf2f(kvls[r + 4][1024 + e0 + d]);
        } else {
            const int nOff = (sr < 4 ? sr : 4) + 1;
            for (int off = 0; off < nOff; off++) {
                float w = sc[r][h2][off];
#pragma unroll
                for (int d = 0; d < 4; d++)
                    o[d] += w * bf2f(kvls[r + 4 - off][1024 + e0 + d]);
            }
        }
        const unsigned short* zg = qkvz + (size_t)(m0 + r) * NQKVZ + 3072 + e0;
        float ss = 0.f;
#pragma unroll
        for (int d = 0; d < 4; d++) {
            float z = bf2f(zg[d]);
            float sg = 1.f / (1.f + expf(-z));
            yv[r][d] = o[d] * sg;
            zs[r][d] = z * sg;
            ss += yv[r][d] * yv[r][d];
        }
        ssr[r] = ss;
    }
    const int wave = t >> 6, lane = t & 63;
#pragma unroll
    for (int r = 0; r < 8; r++)
#pragma unroll
        for (int w = 1; w < 64; w <<= 1) ssr[r] += __shfl_xor(ssr[r], w);
    if (lane == 0) {
#pragma unroll
        for (int r = 0; r < 8; r++) red[wave][r] = ssr[r];
    }
    __syncthreads();
#pragma unroll
    for (int r = 0; r < 8; r++) {
        float tot = red[0][r] + red[1][r] + red[2][r] + red[3][r];
        float rinv = 1.f / sqrtf(tot * (1.0f / 1024.0f) + 1e-6f);
        short4 ov;
        ov.x = f2bf(yv[r][0] * rinv * nw[0] * zs[r][0]);
        ov.y = f2bf(yv[r][1] * rinv * nw[1] * zs[r][1]);
        ov.z = f2bf(yv[r][2] * rinv * nw[2] * zs[r][2]);
        ov.w = f2bf(yv[r][3] * rinv * nw[3] * zs[r][3]);
        ((short4*)yn)[(size_t)(m0 + r) * 256 + t] = ov;
    }
}

extern "C" void kernel_launch(void* const* d_in, const int* in_sizes, int n_in,
                              void* d_out, int out_size, void* d_ws, size_t ws_size,
                              hipStream_t stream) {
    const float* x      = (const float*)d_in[0];
    const float* W_qkv  = (const float*)d_in[1];
    const float* W_z    = (const float*)d_in[2];
    const float* W_b    = (const float*)d_in[3];
    const float* W_a    = (const float*)d_in[4];
    const float* norm_w = (const float*)d_in[5];
    const float* W_out  = (const float*)d_in[6];
    float* out = (float*)d_out;

    // workspace (~135 MB)
    char* ws = (char*)d_ws;
    short* xb    = (short*)ws;          ws += (size_t)MR * H_ * 2;       // 32 MB
    short* Wt1   = (short*)ws;          ws += (size_t)NQKVZ * H_ * 2;    // 16 MB
    short* Wt2   = (short*)ws;          ws += (size_t)H_ * KD_ * 2;      //  4 MB
    unsigned short* qkvzb = (unsigned short*)ws; ws += (size_t)MR * NQKVZ * 2; // 64 MB
    float* bgag  = (float*)ws;          ws += (size_t)MR * 16 * 4;       // 0.5 MB
    short* yn    = (short*)ws;          ws += (size_t)MR * KD_ * 2;      // 16 MB
    float2* ctab = (float2*)ws;         ws += (size_t)S_ * 64 * 8;       //  2 MB

    // 1. ONE prep launch: weight transposes + rope table + x-convert/bgag
    k_mega<<<13312, 256, 0, stream>>>(W_qkv, W_z, W_out, Wt1, Wt2, ctab,
                                      x, xb, W_b, W_a, bgag);
    // 2. GEMM1 (8-phase 256², fused rope epilogue): qkvz = rope(x @ [W_qkv|W_z])
    k_gemm8p<1><<<(MR / 256) * (NQKVZ / 256), 512, 0, stream>>>(
        xb, Wt1, nullptr, qkvzb, ctab, MR, NQKVZ, H_);
    // 3. attention window + gating + RMSNorm -> yn (bf16), 8 rows/block
    k_attn8<<<MR / 8, 256, 0, stream>>>(qkvzb, bgag, norm_w, yn);
    // 4. GEMM2 (8-phase 256x256, coalesced LDS-staged epilogue): out = yn @ W_out
    k_gemm8p<0><<<(MR / 256) * (H_ / 256), 512, 0, stream>>>(
        yn, Wt2, out, nullptr, nullptr, MR, H_, KD_);
}